// Round 7
// baseline (372.289 us; speedup 1.0000x reference)
//
#include <hip/hip_runtime.h>
#include <math.h>

#define BN_SCALE 0.99999500003749967f
#define RRELU_SLOPE 0.22916666666666666f

static __device__ __forceinline__ float leaky(float v) { return v > 0.f ? v : 0.01f * v; }

typedef __attribute__((ext_vector_type(8))) short bf16x8;
typedef __attribute__((ext_vector_type(4))) float f32x4;

static __device__ __forceinline__ unsigned short f2bf(float f) {
  unsigned u = __builtin_bit_cast(unsigned, f);
  u = (u + 0x7FFFu + ((u >> 16) & 1u)) >> 16;
  return (unsigned short)u;
}

// ---------------------------------------------------------------------------
// prep: conv2/conv3 A-frags (bn-folded bf16), Wgagb = fcw @ [W1a|W1b] in
// MFMA B-frag layout (68 k-chunks x 4 n-tiles), folded biases bgagb[64].
// ---------------------------------------------------------------------------
__global__ __launch_bounds__(256) void prep_kernel(
    const float* __restrict__ w2c, const float* __restrict__ g2,
    const float* __restrict__ w3c, const float* __restrict__ g3,
    const float* __restrict__ fcw, const float* __restrict__ fcb,
    const float* __restrict__ w1,  const float* __restrict__ b1,
    unsigned short* __restrict__ w2frag,
    unsigned short* __restrict__ w3frag,
    unsigned short* __restrict__ bfragGG,
    float* __restrict__ bgagb)
{
  const int item = blockIdx.x * 256 + threadIdx.x;
  if (item < 512) {                      // conv2 A-frags: 8 tiles x 64 lanes
    const int tile = item >> 6, lane = item & 63;
    const int mt = tile >> 1, kc = tile & 1;
    const int lr = lane & 15, quad = lane >> 4;
    const int c = mt * 16 + lr;
    const float gs = g2[c] * BN_SCALE;
#pragma unroll
    for (int j = 0; j < 8; ++j) {
      const int k = quad * 8 + j;
      float v;
      if (kc == 0) { const int tap = k >> 4, ci = k & 15; v = w2c[c * 48 + ci * 3 + tap] * gs; }
      else         { v = (k < 16) ? w2c[c * 48 + k * 3 + 2] * gs : 0.f; }
      w2frag[item * 8 + j] = f2bf(v);
    }
  } else if (item < 1664) {              // conv3 A-frags: 18 tiles x 64 lanes
    const int it = item - 512;
    const int tile = it >> 6, lane = it & 63;
    const int mt = tile / 3, tap = tile - mt * 3;
    const int lr = lane & 15, quad = lane >> 4;
    const int c = mt * 16 + lr;
    const float gs = g3[c] * BN_SCALE;
#pragma unroll
    for (int j = 0; j < 8; ++j) {
      const int ci = quad * 8 + j;
      w3frag[it * 8 + j] = f2bf(w3c[c * 96 + ci * 3 + tap] * gs);
    }
  } else if (item < 19072) {             // Wgagb B-frags: 68 chunks x 4 nt x 64
    const int it = item - 1664;
    const int chunk = it >> 8;
    const int rem = it & 255;
    const int nt = rem >> 6;
    const int lane = rem & 63;
    const int lr = lane & 15, quad = lane >> 4;
    const int n = nt * 16 + lr;
    const int off = (n >= 32) ? 32 : 0;
    const int nj = n & 31;
    float w1col[32];
#pragma unroll 8
    for (int q = 0; q < 32; ++q) w1col[q] = w1[(q + off) * 32 + nj];
#pragma unroll
    for (int j = 0; j < 8; ++j) {
      const int k = chunk * 32 + quad * 8 + j;
      float v = 0.f;
      if (k < 2160) {
        const float* fr = fcw + (size_t)k * 32;
#pragma unroll 8
        for (int q = 0; q < 32; ++q) v = fmaf(fr[q], w1col[q], v);
      }
      bfragGG[(size_t)it * 8 + j] = f2bf(v);
    }
  } else if (item < 19136) {             // folded biases
    const int n = item - 19072;
    const int off = (n >= 32) ? 32 : 0;
    const int nj = n & 31;
    float s = (n < 32) ? b1[nj] : 0.f;
    for (int q = 0; q < 32; ++q) s = fmaf(fcb[q], w1[(q + off) * 32 + nj], s);
    bgagb[n] = s;
  }
}

// ---------------------------------------------------------------------------
// fe: wave-autonomous, no barriers, no FC. 1 wave = 1 sequence; block=128
// (2 waves, private 13120 B arenas -> 6 blocks/CU). conv1 fp32 (x from L1)
// -> s1t bf16; conv2/conv3 tap-decomposed MFMA; conv3 epilogue scatters
// pooled bf16 output directly to act3 (stride 2176, zero-padded tail).
// ---------------------------------------------------------------------------
__global__ __launch_bounds__(128) void fe_kernel(
    const float* __restrict__ x,
    const float* __restrict__ w1c, const float* __restrict__ b1c,
    const float* __restrict__ g1,  const float* __restrict__ bb1,
    const float* __restrict__ b2c, const float* __restrict__ g2, const float* __restrict__ bb2,
    const float* __restrict__ b3c, const float* __restrict__ g3, const float* __restrict__ bb3,
    const unsigned short* __restrict__ w2frag,
    const unsigned short* __restrict__ w3frag,
    unsigned short* __restrict__ act3)
{
  __shared__ __align__(16) char smem[2 * 13120];
  const int t = threadIdx.x;
  const int wv = t >> 6, lane = t & 63, quad = lane >> 4, lr = lane & 15;
  const int n = blockIdx.x * 2 + wv;

  char* A = smem + wv * 13120;
  unsigned short* s1t = (unsigned short*)A;           // 194 rows x 16 ch
  unsigned short* s2t = (unsigned short*)(A + 6208);  // 98 rows x 32 ch
  float* be2 = (float*)(A + 12480);                   // 64
  float* be3 = (float*)(A + 12736);                   // 96

  // ---- conv2 A-frags (global, L2-hot) ----
  bf16x8 a2[4][2];
#pragma unroll
  for (int mt = 0; mt < 4; ++mt)
#pragma unroll
    for (int kc = 0; kc < 2; ++kc)
      a2[mt][kc] = *(const bf16x8*)(w2frag + ((mt * 2 + kc) * 64 + lane) * 8);

  // ---- per-wave bias tables + pad zeroing (own-wave writes/reads) ----
  be2[lane] = b2c[lane] * (g2[lane] * BN_SCALE) + bb2[lane];
  be3[lane] = b3c[lane] * (g3[lane] * BN_SCALE) + bb3[lane];
  if (lane < 32) be3[64 + lane] = b3c[64 + lane] * (g3[64 + lane] * BN_SCALE) + bb3[64 + lane];
  ((unsigned*)s1t)[186 * 8 + lane] = 0;           // rows 186..193
  ((unsigned*)s2t)[92 * 16 + lane] = 0;           // rows 92..95
  if (lane < 32) ((unsigned*)s2t)[92 * 16 + 64 + lane] = 0;  // rows 96..97

  // ---- stage 1 weights in registers (lane's fixed cp = lane&7) ----
  const int cp = lane & 7;
  float u[4][3], bbr[4];
#pragma unroll
  for (int d = 0; d < 4; ++d) {
    const int c = cp * 4 + d;
    const float gs = g1[c] * BN_SCALE;
    u[d][0] = w1c[c * 3 + 0] * gs;
    u[d][1] = w1c[c * 3 + 1] * gs;
    u[d][2] = w1c[c * 3 + 2] * gs;
    bbr[d] = b1c[c] * gs + bb1[c];
  }

  // ---- stage 1: conv1+bn+leaky+pool -> s1t[pos][16] bf16 ----
  const float* xr = x + (size_t)n * 375;
  for (int o = lane; o < 1488; o += 64) {
    const int l = o >> 3;
    const int p = 2 * l;
    const float x0 = xr[p], x1 = xr[p + 1], x2 = xr[p + 2], x3 = xr[p + 3];
    unsigned pk = 0;
#pragma unroll
    for (int uu = 0; uu < 2; ++uu) {
      float m = -3.4e38f;
#pragma unroll
      for (int dc = 0; dc < 2; ++dc) {
        const int d = uu * 2 + dc;
        const float v0 = fmaf(x0, u[d][0], fmaf(x1, u[d][1], fmaf(x2, u[d][2], bbr[d])));
        const float v1 = fmaf(x1, u[d][0], fmaf(x2, u[d][1], fmaf(x3, u[d][2], bbr[d])));
        m = fmaxf(m, fmaxf(leaky(v0), leaky(v1)));
      }
      pk |= (unsigned)f2bf(m) << (16 * uu);
    }
    ((unsigned*)s1t)[l * 8 + cp] = pk;
  }

  // ---- preload conv2 bias regs ----
  float be2r[4][4];
#pragma unroll
  for (int mt = 0; mt < 4; ++mt)
#pragma unroll
    for (int r = 0; r < 4; ++r) be2r[mt][r] = be2[mt * 16 + quad * 4 + r];

  // ---- conv2: 12 n-tiles x (2 tap-MFMAs x 4 m-tiles), epilogue -> s2t ----
#pragma unroll 2
  for (int nt = 0; nt < 12; ++nt) {
    const int nrow = nt * 16 + lr;
    bf16x8 b0 = *(const bf16x8*)(s1t + (nrow + (quad >> 1)) * 16 + (quad & 1) * 8);
    bf16x8 b1 = *(const bf16x8*)(s1t + (nrow + 2) * 16 + (quad & 1) * 8);
    f32x4 acc[4];
#pragma unroll
    for (int mt = 0; mt < 4; ++mt)
#pragma unroll
      for (int r = 0; r < 4; ++r) acc[mt][r] = be2r[mt][r];
#pragma unroll
    for (int mt = 0; mt < 4; ++mt)
      acc[mt] = __builtin_amdgcn_mfma_f32_16x16x32_bf16(a2[mt][0], b0, acc[mt], 0, 0, 0);
#pragma unroll
    for (int mt = 0; mt < 4; ++mt)
      acc[mt] = __builtin_amdgcn_mfma_f32_16x16x32_bf16(a2[mt][1], b1, acc[mt], 0, 0, 0);
#pragma unroll
    for (int mt = 0; mt < 4; ++mt) {
      float o[4];
#pragma unroll
      for (int r = 0; r < 4; ++r) {
        const float v = leaky(acc[mt][r]);
        o[r] = fmaxf(v, __shfl_xor(v, 1));          // position pair
      }
      if ((lr & 1) == 0) {
        const int np = nrow >> 1;
        if (np <= 91) {
          const float m0 = fmaxf(o[0], o[1]);       // channel pairs
          const float m1 = fmaxf(o[2], o[3]);
          const unsigned pk = (unsigned)f2bf(m0) | ((unsigned)f2bf(m1) << 16);
          ((unsigned*)s2t)[np * 16 + mt * 4 + quad] = pk;
        }
      }
    }
  }

  // ---- conv3: 6 m-tiles x 6 n-tiles x 3 tap-MFMAs; epilogue -> act3 ----
  unsigned short* actr = act3 + (size_t)n * 2176;
  for (int mt = 0; mt < 6; ++mt) {
    bf16x8 a3[3];
#pragma unroll
    for (int tap = 0; tap < 3; ++tap)
      a3[tap] = *(const bf16x8*)(w3frag + ((mt * 3 + tap) * 64 + lane) * 8);
    float be3r[4];
#pragma unroll
    for (int r = 0; r < 4; ++r) be3r[r] = be3[mt * 16 + quad * 4 + r];
#pragma unroll
    for (int nt = 0; nt < 6; ++nt) {
      const int nrow = nt * 16 + lr;
      f32x4 acc;
#pragma unroll
      for (int r = 0; r < 4; ++r) acc[r] = be3r[r];
#pragma unroll
      for (int tap = 0; tap < 3; ++tap) {
        bf16x8 b = *(const bf16x8*)(s2t + (nrow + tap) * 32 + quad * 8);
        acc = __builtin_amdgcn_mfma_f32_16x16x32_bf16(a3[tap], b, acc, 0, 0, 0);
      }
      float o[4];
#pragma unroll
      for (int r = 0; r < 4; ++r) {
        const float v = leaky(acc[r]);
        o[r] = fmaxf(v, __shfl_xor(v, 1));
      }
      if ((lr & 1) == 0) {
        const int np = nrow >> 1;
        if (np <= 44) {
          const int mp = mt * 8 + quad * 2;
          actr[mp * 45 + np] = f2bf(fmaxf(o[0], o[1]));
          actr[(mp + 1) * 45 + np] = f2bf(fmaxf(o[2], o[3]));
        }
      }
    }
  }
  if (lane < 16) actr[2160 + lane] = 0;   // zero K-pad (2160..2175)
}

// ---------------------------------------------------------------------------
// gagb: [Ga|Gb](4050x64) = act3(4050x2176) @ Wgagb + bgagb via MFMA.
// 64 blocks x 4 waves; wave = 16 rows, 4 n-tiles, K=2176.
// ---------------------------------------------------------------------------
__global__ __launch_bounds__(256) void gagb_kernel(
    const unsigned short* __restrict__ act3,
    const unsigned short* __restrict__ bfragGG,
    const float* __restrict__ bgagb,
    float* __restrict__ Ga, float* __restrict__ Gb)
{
  const int t = threadIdx.x;
  const int wv = t >> 6, lane = t & 63, quad = lane >> 4, lr = lane & 15;
  const int m0 = blockIdx.x * 64 + wv * 16;
  const int arow = min(m0 + lr, 4049);

  f32x4 acc[4] = {};
  for (int chunk = 0; chunk < 68; ++chunk) {
    const bf16x8 a = *(const bf16x8*)(act3 + (size_t)arow * 2176 + chunk * 32 + quad * 8);
#pragma unroll
    for (int nt = 0; nt < 4; ++nt) {
      const bf16x8 b = *(const bf16x8*)(bfragGG + ((size_t)(chunk * 4 + nt) * 64 + lane) * 8);
      acc[nt] = __builtin_amdgcn_mfma_f32_16x16x32_bf16(a, b, acc[nt], 0, 0, 0);
    }
  }
#pragma unroll
  for (int nt = 0; nt < 4; ++nt) {
    const int col = nt * 16 + lr;
    const float bias = bgagb[col];
#pragma unroll
    for (int r = 0; r < 4; ++r) {
      const int row = m0 + quad * 4 + r;
      if (row < 4050) {
        const float v = acc[nt][r] + bias;
        if (col < 32) Ga[row * 32 + col] = v;
        else          Gb[row * 32 + (col - 32)] = v;
      }
    }
  }
}

// ---------------------------------------------------------------------------
// sim: 480 blocks = 30 subjects x 16 chunks; Ga/Gb staged in LDS (stride 36);
// h1 = relu(Ga[i]+Gb[j]); 32->16->8->1 + tanh.
// ---------------------------------------------------------------------------
__global__ __launch_bounds__(256) void sim_kernel(
    const float* __restrict__ Ga, const float* __restrict__ Gb,
    const float* __restrict__ w2, const float* __restrict__ b2,
    const float* __restrict__ w3, const float* __restrict__ b3,
    const float* __restrict__ w4, const float* __restrict__ b4,
    float* __restrict__ subjects)
{
  __shared__ float sGa[135 * 36];
  __shared__ float sGb[135 * 36];
  __shared__ float sw2[512], sw3[128], sw4[8];
  __shared__ float sb2[16], sb3[8], sb4v[1];

  const int t = threadIdx.x;
  const int b = blockIdx.x >> 4;
  const int c = blockIdx.x & 15;

  for (int i = t; i < 4320; i += 256) {
    const int r = i >> 5, col = i & 31;
    sGa[r * 36 + col] = Ga[b * 4320 + i];
    sGb[r * 36 + col] = Gb[b * 4320 + i];
  }
  for (int i = t; i < 512; i += 256) sw2[i] = w2[i];
  if (t < 128) sw3[t] = w3[t];
  if (t < 8) sw4[t] = w4[t];
  if (t < 16) sb2[t] = b2[t];
  if (t < 8) sb3[t] = b3[t];
  if (t == 0) sb4v[0] = b4[0];
  __syncthreads();

  const int pend = min(9045, (c + 1) * 566);
  for (int p = c * 566 + t; p < pend; p += 256) {
    int i = (int)((269.0f - sqrtf((float)(72361 - 8 * p))) * 0.5f);
    i = max(0, min(133, i));
    while (134 * (i + 1) - ((i + 1) * i) / 2 <= p) ++i;
    while (134 * i - (i * (i - 1)) / 2 > p) --i;
    const int j = i + 1 + (p - (134 * i - (i * (i - 1)) / 2));

    float h1[32];
#pragma unroll
    for (int q = 0; q < 8; ++q) {
      const float4 va = *(const float4*)(&sGa[i * 36 + 4 * q]);
      const float4 vb = *(const float4*)(&sGb[j * 36 + 4 * q]);
      h1[4 * q + 0] = fmaxf(va.x + vb.x, 0.f);
      h1[4 * q + 1] = fmaxf(va.y + vb.y, 0.f);
      h1[4 * q + 2] = fmaxf(va.z + vb.z, 0.f);
      h1[4 * q + 3] = fmaxf(va.w + vb.w, 0.f);
    }

    float h2[16];
#pragma unroll
    for (int jj = 0; jj < 16; ++jj) h2[jj] = sb2[jj];
#pragma unroll 8
    for (int ii = 0; ii < 32; ++ii) {
      const float av = h1[ii];
      const float4* wr = reinterpret_cast<const float4*>(&sw2[ii * 16]);
#pragma unroll
      for (int r = 0; r < 4; ++r) {
        float4 w = wr[r];
        h2[4 * r + 0] = fmaf(av, w.x, h2[4 * r + 0]);
        h2[4 * r + 1] = fmaf(av, w.y, h2[4 * r + 1]);
        h2[4 * r + 2] = fmaf(av, w.z, h2[4 * r + 2]);
        h2[4 * r + 3] = fmaf(av, w.w, h2[4 * r + 3]);
      }
    }
#pragma unroll
    for (int jj = 0; jj < 16; ++jj) h2[jj] = fmaxf(h2[jj], 0.f);

    float h3[8];
#pragma unroll
    for (int jj = 0; jj < 8; ++jj) h3[jj] = sb3[jj];
#pragma unroll
    for (int ii = 0; ii < 16; ++ii) {
      const float av = h2[ii];
      const float4* wr = reinterpret_cast<const float4*>(&sw3[ii * 8]);
#pragma unroll
      for (int r = 0; r < 2; ++r) {
        float4 w = wr[r];
        h3[4 * r + 0] = fmaf(av, w.x, h3[4 * r + 0]);
        h3[4 * r + 1] = fmaf(av, w.y, h3[4 * r + 1]);
        h3[4 * r + 2] = fmaf(av, w.z, h3[4 * r + 2]);
        h3[4 * r + 3] = fmaf(av, w.w, h3[4 * r + 3]);
      }
    }
#pragma unroll
    for (int jj = 0; jj < 8; ++jj) h3[jj] = fmaxf(h3[jj], 0.f);

    float z = sb4v[0];
#pragma unroll
    for (int ii = 0; ii < 8; ++ii) z = fmaf(h3[ii], sw4[ii], z);

    const float az = fabsf(z);
    const float e = __expf(-2.f * az);
    const float r = (1.f - e) / (1.f + e);
    subjects[b * 9045 + p] = copysignf(r, z);
  }
}

// ---------------------------------------------------------------------------
// cls layer 1: 512 blocks = 64 k-chunks x 8 col-groups of 128; 2 k-halves
// reduced via LDS; subjects loads wave-uniform -> scalar pipe.
// ---------------------------------------------------------------------------
__global__ __launch_bounds__(256) void c1_kernel(
    const float* __restrict__ subjects,
    const float* __restrict__ w1,
    float* __restrict__ part)
{
  __shared__ float red[30 * 128];
  const int q = blockIdx.x >> 3;
  const int g = blockIdx.x & 7;
  const int t = threadIdx.x;
  const int col = g * 128 + (t & 127);
  const int ks = t >> 7;
  const int k0 = q * 142;
  const int nk = min(9045, k0 + 142) - k0;
  const int half = (nk + 1) >> 1;
  const int ka = ks ? half : 0;
  const int kb = ks ? nk : half;

  float acc[30];
#pragma unroll
  for (int r = 0; r < 30; ++r) acc[r] = 0.f;

  for (int kk = ka; kk < kb; ++kk) {
    const int k = k0 + kk;
    const float w = w1[(size_t)k * 1024 + col];
#pragma unroll
    for (int r = 0; r < 30; ++r)
      acc[r] = fmaf(subjects[r * 9045 + k], w, acc[r]);
  }
  if (ks == 1) {
#pragma unroll
    for (int r = 0; r < 30; ++r) red[r * 128 + (t & 127)] = acc[r];
  }
  __syncthreads();
  if (ks == 0) {
#pragma unroll
    for (int r = 0; r < 30; ++r)
      part[(size_t)(r * 64 + q) * 1024 + col] = acc[r] + red[r * 128 + (t & 127)];
  }
}

// ---------------------------------------------------------------------------
// tail (merged): reduce partials + rrelu -> 1024->256->64->3 + log_softmax.
// 30 blocks, one per subject row.
// ---------------------------------------------------------------------------
__global__ __launch_bounds__(256) void tail_kernel(
    const float* __restrict__ part,
    const float* __restrict__ cb1,
    const float* __restrict__ w2, const float* __restrict__ cb2,
    const float* __restrict__ w3, const float* __restrict__ cb3,
    const float* __restrict__ w4, const float* __restrict__ cb4,
    float* __restrict__ out)
{
  __shared__ float sc1[1024];
  __shared__ float sc2[256];
  __shared__ float sc3[64];
  __shared__ float slg[3];
  const int r = blockIdx.x, t = threadIdx.x;

  for (int j = t; j < 1024; j += 256) {
    float s = cb1[j];
    const float* pp = part + (size_t)r * 64 * 1024 + j;
#pragma unroll 4
    for (int q = 0; q < 64; ++q) s += pp[q * 1024];
    sc1[j] = s >= 0.f ? s : RRELU_SLOPE * s;
  }
  __syncthreads();
  {
    float a0 = cb2[t], a1 = 0.f, a2v = 0.f, a3v = 0.f;
    for (int kk = 0; kk < 1024; kk += 4) {
      const float4 a = *reinterpret_cast<const float4*>(&sc1[kk]);
      a0  = fmaf(a.x, w2[(kk + 0) * 256 + t], a0);
      a1  = fmaf(a.y, w2[(kk + 1) * 256 + t], a1);
      a2v = fmaf(a.z, w2[(kk + 2) * 256 + t], a2v);
      a3v = fmaf(a.w, w2[(kk + 3) * 256 + t], a3v);
    }
    sc2[t] = fmaxf((a0 + a1) + (a2v + a3v), 0.f);
  }
  __syncthreads();
  if (t < 64) {
    float a0 = cb3[t], a1 = 0.f;
#pragma unroll 2
    for (int kk = 0; kk < 256; kk += 2) {
      a0 = fmaf(sc2[kk], w3[kk * 64 + t], a0);
      a1 = fmaf(sc2[kk + 1], w3[(kk + 1) * 64 + t], a1);
    }
    sc3[t] = fmaxf(a0 + a1, 0.f);
  }
  __syncthreads();
  if (t < 3) {
    float acc = cb4[t];
#pragma unroll
    for (int kk = 0; kk < 64; ++kk) acc = fmaf(sc3[kk], w4[kk * 3 + t], acc);
    slg[t] = acc;
  }
  __syncthreads();
  if (t == 0) {
    float m = fmaxf(slg[0], fmaxf(slg[1], slg[2]));
    float se = __expf(slg[0] - m) + __expf(slg[1] - m) + __expf(slg[2] - m);
    float lse = m + logf(se);
    out[r * 3 + 0] = slg[0] - lse;
    out[r * 3 + 1] = slg[1] - lse;
    out[r * 3 + 2] = slg[2] - lse;
  }
}

extern "C" void kernel_launch(void* const* d_in, const int* in_sizes, int n_in,
                              void* d_out, int out_size, void* d_ws, size_t ws_size,
                              hipStream_t stream) {
  const float* x    = (const float*)d_in[0];
  const float* w1c  = (const float*)d_in[1];
  const float* b1c  = (const float*)d_in[2];
  const float* g1   = (const float*)d_in[3];
  const float* bb1  = (const float*)d_in[4];
  const float* w2c  = (const float*)d_in[5];
  const float* b2c  = (const float*)d_in[6];
  const float* g2   = (const float*)d_in[7];
  const float* bb2  = (const float*)d_in[8];
  const float* w3c  = (const float*)d_in[9];
  const float* b3c  = (const float*)d_in[10];
  const float* g3   = (const float*)d_in[11];
  const float* bb3  = (const float*)d_in[12];
  const float* fcw  = (const float*)d_in[13];
  const float* fcb  = (const float*)d_in[14];
  const float* sw1  = (const float*)d_in[15];
  const float* sb1  = (const float*)d_in[16];
  const float* sw2  = (const float*)d_in[17];
  const float* sb2  = (const float*)d_in[18];
  const float* sw3  = (const float*)d_in[19];
  const float* sb3  = (const float*)d_in[20];
  const float* sw4  = (const float*)d_in[21];
  const float* sb4  = (const float*)d_in[22];
  const float* cw1  = (const float*)d_in[23];
  const float* cb1  = (const float*)d_in[24];
  const float* cw2  = (const float*)d_in[25];
  const float* cb2  = (const float*)d_in[26];
  const float* cw3  = (const float*)d_in[27];
  const float* cb3  = (const float*)d_in[28];
  const float* cw4  = (const float*)d_in[29];
  const float* cb4  = (const float*)d_in[30];

  float* ws = (float*)d_ws;
  float* Ga       = ws;                  // 129600
  float* Gb       = ws + 129600;         // 129600 -> 259200
  float* subjects = ws + 259200;         // 271350 -> 530550
  float* part     = ws + 530560;         // 30*64*1024 = 1966080 -> 2496640
  float* bgagb    = ws + 2496640;        // 64 -> 2496704
  unsigned short* wsu = (unsigned short*)(ws + 2496704);
  unsigned short* w2frag  = wsu;               // 4096 sh
  unsigned short* w3frag  = wsu + 4096;        // 9216 sh
  unsigned short* bfragGG = wsu + 13312;       // 139264 sh
  unsigned short* act3    = wsu + 152576;      // 4050*2176 = 8812800 sh

  prep_kernel<<<75, 256, 0, stream>>>(w2c, g2, w3c, g3, fcw, fcb, sw1, sb1,
                                      w2frag, w3frag, bfragGG, bgagb);
  fe_kernel<<<2025, 128, 0, stream>>>(x, w1c, b1c, g1, bb1, b2c, g2, bb2,
                                      b3c, g3, bb3, w2frag, w3frag, act3);
  gagb_kernel<<<64, 256, 0, stream>>>(act3, bfragGG, bgagb, Ga, Gb);
  sim_kernel<<<480, 256, 0, stream>>>(Ga, Gb, sw2, sb2, sw3, sb3, sw4, sb4, subjects);
  c1_kernel<<<512, 256, 0, stream>>>(subjects, cw1, part);
  tail_kernel<<<30, 256, 0, stream>>>(part, cb1, cw2, cb2, cw3, cb3, cw4, cb4, (float*)d_out);
}

// Round 8
// 337.355 us; speedup vs baseline: 1.1036x; 1.1036x over previous
//
#include <hip/hip_runtime.h>
#include <math.h>

#define BN_SCALE 0.99999500003749967f
#define RRELU_SLOPE 0.22916666666666666f

static __device__ __forceinline__ float leaky(float v) { return v > 0.f ? v : 0.01f * v; }

typedef __attribute__((ext_vector_type(8))) short bf16x8;
typedef __attribute__((ext_vector_type(4))) float f32x4;

static __device__ __forceinline__ unsigned short f2bf(float f) {
  unsigned u = __builtin_bit_cast(unsigned, f);
  u = (u + 0x7FFFu + ((u >> 16) & 1u)) >> 16;
  return (unsigned short)u;
}

// ---------------------------------------------------------------------------
// prep: conv2/conv3 A-frags (bn-folded bf16), Wgagb = fcw @ [W1a|W1b] in
// MFMA B-frag layout (68 k-chunks x 4 n-tiles), folded biases bgagb[64].
// ---------------------------------------------------------------------------
__global__ __launch_bounds__(256) void prep_kernel(
    const float* __restrict__ w2c, const float* __restrict__ g2,
    const float* __restrict__ w3c, const float* __restrict__ g3,
    const float* __restrict__ fcw, const float* __restrict__ fcb,
    const float* __restrict__ w1,  const float* __restrict__ b1,
    unsigned short* __restrict__ w2frag,
    unsigned short* __restrict__ w3frag,
    unsigned short* __restrict__ bfragGG,
    float* __restrict__ bgagb)
{
  const int item = blockIdx.x * 256 + threadIdx.x;
  if (item < 512) {                      // conv2 A-frags: 8 tiles x 64 lanes
    const int tile = item >> 6, lane = item & 63;
    const int mt = tile >> 1, kc = tile & 1;
    const int lr = lane & 15, quad = lane >> 4;
    const int c = mt * 16 + lr;
    const float gs = g2[c] * BN_SCALE;
#pragma unroll
    for (int j = 0; j < 8; ++j) {
      const int k = quad * 8 + j;
      float v;
      if (kc == 0) { const int tap = k >> 4, ci = k & 15; v = w2c[c * 48 + ci * 3 + tap] * gs; }
      else         { v = (k < 16) ? w2c[c * 48 + k * 3 + 2] * gs : 0.f; }
      w2frag[item * 8 + j] = f2bf(v);
    }
  } else if (item < 1664) {              // conv3 A-frags: 18 tiles x 64 lanes
    const int it = item - 512;
    const int tile = it >> 6, lane = it & 63;
    const int mt = tile / 3, tap = tile - mt * 3;
    const int lr = lane & 15, quad = lane >> 4;
    const int c = mt * 16 + lr;
    const float gs = g3[c] * BN_SCALE;
#pragma unroll
    for (int j = 0; j < 8; ++j) {
      const int ci = quad * 8 + j;
      w3frag[it * 8 + j] = f2bf(w3c[c * 96 + ci * 3 + tap] * gs);
    }
  } else if (item < 19072) {             // Wgagb B-frags: 68 chunks x 4 nt x 64
    const int it = item - 1664;
    const int chunk = it >> 8;
    const int rem = it & 255;
    const int nt = rem >> 6;
    const int lane = rem & 63;
    const int lr = lane & 15, quad = lane >> 4;
    const int n = nt * 16 + lr;
    const int off = (n >= 32) ? 32 : 0;
    const int nj = n & 31;
    float w1col[32];
#pragma unroll 8
    for (int q = 0; q < 32; ++q) w1col[q] = w1[(q + off) * 32 + nj];
#pragma unroll
    for (int j = 0; j < 8; ++j) {
      const int k = chunk * 32 + quad * 8 + j;
      float v = 0.f;
      if (k < 2160) {
        const float* fr = fcw + (size_t)k * 32;
#pragma unroll 8
        for (int q = 0; q < 32; ++q) v = fmaf(fr[q], w1col[q], v);
      }
      bfragGG[(size_t)it * 8 + j] = f2bf(v);
    }
  } else if (item < 19136) {             // folded biases
    const int n = item - 19072;
    const int off = (n >= 32) ? 32 : 0;
    const int nj = n & 31;
    float s = (n < 32) ? b1[nj] : 0.f;
    for (int q = 0; q < 32; ++q) s = fmaf(fcb[q], w1[(q + off) * 32 + nj], s);
    bgagb[n] = s;
  }
}

// ---------------------------------------------------------------------------
// fe: wave-autonomous, no barriers, no FC. 1 wave = 1 sequence; block=128
// (2 waves, private 13120 B arenas). conv3 epilogue scatters pooled bf16
// output directly to act3 (stride 2176, zero-padded tail).
// ---------------------------------------------------------------------------
__global__ __launch_bounds__(128) void fe_kernel(
    const float* __restrict__ x,
    const float* __restrict__ w1c, const float* __restrict__ b1c,
    const float* __restrict__ g1,  const float* __restrict__ bb1,
    const float* __restrict__ b2c, const float* __restrict__ g2, const float* __restrict__ bb2,
    const float* __restrict__ b3c, const float* __restrict__ g3, const float* __restrict__ bb3,
    const unsigned short* __restrict__ w2frag,
    const unsigned short* __restrict__ w3frag,
    unsigned short* __restrict__ act3)
{
  __shared__ __align__(16) char smem[2 * 13120];
  const int t = threadIdx.x;
  const int wv = t >> 6, lane = t & 63, quad = lane >> 4, lr = lane & 15;
  const int n = blockIdx.x * 2 + wv;

  char* A = smem + wv * 13120;
  unsigned short* s1t = (unsigned short*)A;           // 194 rows x 16 ch
  unsigned short* s2t = (unsigned short*)(A + 6208);  // 98 rows x 32 ch
  float* be2 = (float*)(A + 12480);                   // 64
  float* be3 = (float*)(A + 12736);                   // 96

  bf16x8 a2[4][2];
#pragma unroll
  for (int mt = 0; mt < 4; ++mt)
#pragma unroll
    for (int kc = 0; kc < 2; ++kc)
      a2[mt][kc] = *(const bf16x8*)(w2frag + ((mt * 2 + kc) * 64 + lane) * 8);

  be2[lane] = b2c[lane] * (g2[lane] * BN_SCALE) + bb2[lane];
  be3[lane] = b3c[lane] * (g3[lane] * BN_SCALE) + bb3[lane];
  if (lane < 32) be3[64 + lane] = b3c[64 + lane] * (g3[64 + lane] * BN_SCALE) + bb3[64 + lane];
  ((unsigned*)s1t)[186 * 8 + lane] = 0;
  ((unsigned*)s2t)[92 * 16 + lane] = 0;
  if (lane < 32) ((unsigned*)s2t)[92 * 16 + 64 + lane] = 0;

  const int cp = lane & 7;
  float u[4][3], bbr[4];
#pragma unroll
  for (int d = 0; d < 4; ++d) {
    const int c = cp * 4 + d;
    const float gs = g1[c] * BN_SCALE;
    u[d][0] = w1c[c * 3 + 0] * gs;
    u[d][1] = w1c[c * 3 + 1] * gs;
    u[d][2] = w1c[c * 3 + 2] * gs;
    bbr[d] = b1c[c] * gs + bb1[c];
  }

  const float* xr = x + (size_t)n * 375;
  for (int o = lane; o < 1488; o += 64) {
    const int l = o >> 3;
    const int p = 2 * l;
    const float x0 = xr[p], x1 = xr[p + 1], x2 = xr[p + 2], x3 = xr[p + 3];
    unsigned pk = 0;
#pragma unroll
    for (int uu = 0; uu < 2; ++uu) {
      float m = -3.4e38f;
#pragma unroll
      for (int dc = 0; dc < 2; ++dc) {
        const int d = uu * 2 + dc;
        const float v0 = fmaf(x0, u[d][0], fmaf(x1, u[d][1], fmaf(x2, u[d][2], bbr[d])));
        const float v1 = fmaf(x1, u[d][0], fmaf(x2, u[d][1], fmaf(x3, u[d][2], bbr[d])));
        m = fmaxf(m, fmaxf(leaky(v0), leaky(v1)));
      }
      pk |= (unsigned)f2bf(m) << (16 * uu);
    }
    ((unsigned*)s1t)[l * 8 + cp] = pk;
  }

  float be2r[4][4];
#pragma unroll
  for (int mt = 0; mt < 4; ++mt)
#pragma unroll
    for (int r = 0; r < 4; ++r) be2r[mt][r] = be2[mt * 16 + quad * 4 + r];

#pragma unroll 2
  for (int nt = 0; nt < 12; ++nt) {
    const int nrow = nt * 16 + lr;
    bf16x8 b0 = *(const bf16x8*)(s1t + (nrow + (quad >> 1)) * 16 + (quad & 1) * 8);
    bf16x8 b1 = *(const bf16x8*)(s1t + (nrow + 2) * 16 + (quad & 1) * 8);
    f32x4 acc[4];
#pragma unroll
    for (int mt = 0; mt < 4; ++mt)
#pragma unroll
      for (int r = 0; r < 4; ++r) acc[mt][r] = be2r[mt][r];
#pragma unroll
    for (int mt = 0; mt < 4; ++mt)
      acc[mt] = __builtin_amdgcn_mfma_f32_16x16x32_bf16(a2[mt][0], b0, acc[mt], 0, 0, 0);
#pragma unroll
    for (int mt = 0; mt < 4; ++mt)
      acc[mt] = __builtin_amdgcn_mfma_f32_16x16x32_bf16(a2[mt][1], b1, acc[mt], 0, 0, 0);
#pragma unroll
    for (int mt = 0; mt < 4; ++mt) {
      float o[4];
#pragma unroll
      for (int r = 0; r < 4; ++r) {
        const float v = leaky(acc[mt][r]);
        o[r] = fmaxf(v, __shfl_xor(v, 1));
      }
      if ((lr & 1) == 0) {
        const int np = nrow >> 1;
        if (np <= 91) {
          const float m0 = fmaxf(o[0], o[1]);
          const float m1 = fmaxf(o[2], o[3]);
          const unsigned pk = (unsigned)f2bf(m0) | ((unsigned)f2bf(m1) << 16);
          ((unsigned*)s2t)[np * 16 + mt * 4 + quad] = pk;
        }
      }
    }
  }

  unsigned short* actr = act3 + (size_t)n * 2176;
  for (int mt = 0; mt < 6; ++mt) {
    bf16x8 a3[3];
#pragma unroll
    for (int tap = 0; tap < 3; ++tap)
      a3[tap] = *(const bf16x8*)(w3frag + ((mt * 3 + tap) * 64 + lane) * 8);
    float be3r[4];
#pragma unroll
    for (int r = 0; r < 4; ++r) be3r[r] = be3[mt * 16 + quad * 4 + r];
#pragma unroll
    for (int nt = 0; nt < 6; ++nt) {
      const int nrow = nt * 16 + lr;
      f32x4 acc;
#pragma unroll
      for (int r = 0; r < 4; ++r) acc[r] = be3r[r];
#pragma unroll
      for (int tap = 0; tap < 3; ++tap) {
        bf16x8 b = *(const bf16x8*)(s2t + (nrow + tap) * 32 + quad * 8);
        acc = __builtin_amdgcn_mfma_f32_16x16x32_bf16(a3[tap], b, acc, 0, 0, 0);
      }
      float o[4];
#pragma unroll
      for (int r = 0; r < 4; ++r) {
        const float v = leaky(acc[r]);
        o[r] = fmaxf(v, __shfl_xor(v, 1));
      }
      if ((lr & 1) == 0) {
        const int np = nrow >> 1;
        if (np <= 44) {
          const int mp = mt * 8 + quad * 2;
          actr[mp * 45 + np] = f2bf(fmaxf(o[0], o[1]));
          actr[(mp + 1) * 45 + np] = f2bf(fmaxf(o[2], o[3]));
        }
      }
    }
  }
  if (lane < 16) actr[2160 + lane] = 0;
}

// ---------------------------------------------------------------------------
// gagb: [Ga|Gb](4050x64) = act3(4050x2176) @ Wgagb + bgagb via MFMA.
// ---------------------------------------------------------------------------
__global__ __launch_bounds__(256) void gagb_kernel(
    const unsigned short* __restrict__ act3,
    const unsigned short* __restrict__ bfragGG,
    const float* __restrict__ bgagb,
    float* __restrict__ Ga, float* __restrict__ Gb)
{
  const int t = threadIdx.x;
  const int wv = t >> 6, lane = t & 63, quad = lane >> 4, lr = lane & 15;
  const int m0 = blockIdx.x * 64 + wv * 16;
  const int arow = min(m0 + lr, 4049);

  f32x4 acc[4] = {};
  for (int chunk = 0; chunk < 68; ++chunk) {
    const bf16x8 a = *(const bf16x8*)(act3 + (size_t)arow * 2176 + chunk * 32 + quad * 8);
#pragma unroll
    for (int nt = 0; nt < 4; ++nt) {
      const bf16x8 b = *(const bf16x8*)(bfragGG + ((size_t)(chunk * 4 + nt) * 64 + lane) * 8);
      acc[nt] = __builtin_amdgcn_mfma_f32_16x16x32_bf16(a, b, acc[nt], 0, 0, 0);
    }
  }
#pragma unroll
  for (int nt = 0; nt < 4; ++nt) {
    const int col = nt * 16 + lr;
    const float bias = bgagb[col];
#pragma unroll
    for (int r = 0; r < 4; ++r) {
      const int row = m0 + quad * 4 + r;
      if (row < 4050) {
        const float v = acc[nt][r] + bias;
        if (col < 32) Ga[row * 32 + col] = v;
        else          Gb[row * 32 + (col - 32)] = v;
      }
    }
  }
}

// ---------------------------------------------------------------------------
// sim: 480 blocks = 30 subjects x 16 chunks; Ga/Gb staged in LDS.
// ---------------------------------------------------------------------------
__global__ __launch_bounds__(256) void sim_kernel(
    const float* __restrict__ Ga, const float* __restrict__ Gb,
    const float* __restrict__ w2, const float* __restrict__ b2,
    const float* __restrict__ w3, const float* __restrict__ b3,
    const float* __restrict__ w4, const float* __restrict__ b4,
    float* __restrict__ subjects)
{
  __shared__ float sGa[135 * 36];
  __shared__ float sGb[135 * 36];
  __shared__ float sw2[512], sw3[128], sw4[8];
  __shared__ float sb2[16], sb3[8], sb4v[1];

  const int t = threadIdx.x;
  const int b = blockIdx.x >> 4;
  const int c = blockIdx.x & 15;

  for (int i = t; i < 4320; i += 256) {
    const int r = i >> 5, col = i & 31;
    sGa[r * 36 + col] = Ga[b * 4320 + i];
    sGb[r * 36 + col] = Gb[b * 4320 + i];
  }
  for (int i = t; i < 512; i += 256) sw2[i] = w2[i];
  if (t < 128) sw3[t] = w3[t];
  if (t < 8) sw4[t] = w4[t];
  if (t < 16) sb2[t] = b2[t];
  if (t < 8) sb3[t] = b3[t];
  if (t == 0) sb4v[0] = b4[0];
  __syncthreads();

  const int pend = min(9045, (c + 1) * 566);
  for (int p = c * 566 + t; p < pend; p += 256) {
    int i = (int)((269.0f - sqrtf((float)(72361 - 8 * p))) * 0.5f);
    i = max(0, min(133, i));
    while (134 * (i + 1) - ((i + 1) * i) / 2 <= p) ++i;
    while (134 * i - (i * (i - 1)) / 2 > p) --i;
    const int j = i + 1 + (p - (134 * i - (i * (i - 1)) / 2));

    float h1[32];
#pragma unroll
    for (int q = 0; q < 8; ++q) {
      const float4 va = *(const float4*)(&sGa[i * 36 + 4 * q]);
      const float4 vb = *(const float4*)(&sGb[j * 36 + 4 * q]);
      h1[4 * q + 0] = fmaxf(va.x + vb.x, 0.f);
      h1[4 * q + 1] = fmaxf(va.y + vb.y, 0.f);
      h1[4 * q + 2] = fmaxf(va.z + vb.z, 0.f);
      h1[4 * q + 3] = fmaxf(va.w + vb.w, 0.f);
    }

    float h2[16];
#pragma unroll
    for (int jj = 0; jj < 16; ++jj) h2[jj] = sb2[jj];
#pragma unroll 8
    for (int ii = 0; ii < 32; ++ii) {
      const float av = h1[ii];
      const float4* wr = reinterpret_cast<const float4*>(&sw2[ii * 16]);
#pragma unroll
      for (int r = 0; r < 4; ++r) {
        float4 w = wr[r];
        h2[4 * r + 0] = fmaf(av, w.x, h2[4 * r + 0]);
        h2[4 * r + 1] = fmaf(av, w.y, h2[4 * r + 1]);
        h2[4 * r + 2] = fmaf(av, w.z, h2[4 * r + 2]);
        h2[4 * r + 3] = fmaf(av, w.w, h2[4 * r + 3]);
      }
    }
#pragma unroll
    for (int jj = 0; jj < 16; ++jj) h2[jj] = fmaxf(h2[jj], 0.f);

    float h3[8];
#pragma unroll
    for (int jj = 0; jj < 8; ++jj) h3[jj] = sb3[jj];
#pragma unroll
    for (int ii = 0; ii < 16; ++ii) {
      const float av = h2[ii];
      const float4* wr = reinterpret_cast<const float4*>(&sw3[ii * 8]);
#pragma unroll
      for (int r = 0; r < 2; ++r) {
        float4 w = wr[r];
        h3[4 * r + 0] = fmaf(av, w.x, h3[4 * r + 0]);
        h3[4 * r + 1] = fmaf(av, w.y, h3[4 * r + 1]);
        h3[4 * r + 2] = fmaf(av, w.z, h3[4 * r + 2]);
        h3[4 * r + 3] = fmaf(av, w.w, h3[4 * r + 3]);
      }
    }
#pragma unroll
    for (int jj = 0; jj < 8; ++jj) h3[jj] = fmaxf(h3[jj], 0.f);

    float z = sb4v[0];
#pragma unroll
    for (int ii = 0; ii < 8; ++ii) z = fmaf(h3[ii], sw4[ii], z);

    const float az = fabsf(z);
    const float e = __expf(-2.f * az);
    const float r = (1.f - e) / (1.f + e);
    subjects[b * 9045 + p] = copysignf(r, z);
  }
}

// ---------------------------------------------------------------------------
// cls layer 1: 512 blocks = 64 k-chunks x 8 col-groups of 128.
// ---------------------------------------------------------------------------
__global__ __launch_bounds__(256) void c1_kernel(
    const float* __restrict__ subjects,
    const float* __restrict__ w1,
    float* __restrict__ part)
{
  __shared__ float red[30 * 128];
  const int q = blockIdx.x >> 3;
  const int g = blockIdx.x & 7;
  const int t = threadIdx.x;
  const int col = g * 128 + (t & 127);
  const int ks = t >> 7;
  const int k0 = q * 142;
  const int nk = min(9045, k0 + 142) - k0;
  const int half = (nk + 1) >> 1;
  const int ka = ks ? half : 0;
  const int kb = ks ? nk : half;

  float acc[30];
#pragma unroll
  for (int r = 0; r < 30; ++r) acc[r] = 0.f;

  for (int kk = ka; kk < kb; ++kk) {
    const int k = k0 + kk;
    const float w = w1[(size_t)k * 1024 + col];
#pragma unroll
    for (int r = 0; r < 30; ++r)
      acc[r] = fmaf(subjects[r * 9045 + k], w, acc[r]);
  }
  if (ks == 1) {
#pragma unroll
    for (int r = 0; r < 30; ++r) red[r * 128 + (t & 127)] = acc[r];
  }
  __syncthreads();
  if (ks == 0) {
#pragma unroll
    for (int r = 0; r < 30; ++r)
      part[(size_t)(r * 64 + q) * 1024 + col] = acc[r] + red[r * 128 + (t & 127)];
  }
}

// ---------------------------------------------------------------------------
// tail_a: reduce 64 partials + rrelu -> act1[30][1024]. 120 blocks.
// ---------------------------------------------------------------------------
__global__ __launch_bounds__(256) void tail_a_kernel(
    const float* __restrict__ part,
    const float* __restrict__ cb1,
    float* __restrict__ act1)
{
  const int r = blockIdx.x >> 2;
  const int cg = blockIdx.x & 3;
  const int j = cg * 256 + threadIdx.x;
  float s = cb1[j];
  const float* pp = part + (size_t)r * 64 * 1024 + j;
#pragma unroll 8
  for (int q = 0; q < 64; ++q) s += pp[q * 1024];
  act1[r * 1024 + j] = s >= 0.f ? s : RRELU_SLOPE * s;
}

// ---------------------------------------------------------------------------
// tail_b: GEMM2 (1024->256) + relu -> act2. 240 blocks = 30 rows x 8
// col-groups of 32; block = 32 cols x 8 k-splits of 128; LDS reduce.
// ---------------------------------------------------------------------------
__global__ __launch_bounds__(256) void tail_b_kernel(
    const float* __restrict__ act1,
    const float* __restrict__ w2, const float* __restrict__ cb2,
    float* __restrict__ act2)
{
  __shared__ float sa[1024];
  __shared__ float sp[256];
  const int r = blockIdx.x >> 3;
  const int cg = blockIdx.x & 7;
  const int t = threadIdx.x;
  const int c = t & 31;
  const int ks = t >> 5;
  const int col = cg * 32 + c;

  for (int i = t; i < 1024; i += 256) sa[i] = act1[r * 1024 + i];
  __syncthreads();

  float acc = 0.f;
  const int k0 = ks * 128;
  for (int kk = k0; kk < k0 + 128; kk += 4) {
    const float4 a = *reinterpret_cast<const float4*>(&sa[kk]);
    acc = fmaf(a.x, w2[(kk + 0) * 256 + col], acc);
    acc = fmaf(a.y, w2[(kk + 1) * 256 + col], acc);
    acc = fmaf(a.z, w2[(kk + 2) * 256 + col], acc);
    acc = fmaf(a.w, w2[(kk + 3) * 256 + col], acc);
  }
  sp[t] = acc;
  __syncthreads();
  if (t < 32) {
    float s = cb2[col];
#pragma unroll
    for (int q = 0; q < 8; ++q) s += sp[q * 32 + t];
    act2[r * 256 + cg * 32 + t] = fmaxf(s, 0.f);
  }
}

// ---------------------------------------------------------------------------
// tail_c: GEMM3 (256->64, 4-way k-split) + GEMM4 (64->3) + log_softmax.
// 30 blocks.
// ---------------------------------------------------------------------------
__global__ __launch_bounds__(256) void tail_c_kernel(
    const float* __restrict__ act2,
    const float* __restrict__ w3, const float* __restrict__ cb3,
    const float* __restrict__ w4, const float* __restrict__ cb4,
    float* __restrict__ out)
{
  __shared__ float sa[256];
  __shared__ float sp[256];
  __shared__ float sc3[64];
  __shared__ float slg[3];
  const int r = blockIdx.x, t = threadIdx.x;
  const int c = t & 63;
  const int ks = t >> 6;

  sa[t] = act2[r * 256 + t];
  __syncthreads();
  {
    float acc = 0.f;
    const int k0 = ks * 64;
#pragma unroll 4
    for (int kk = k0; kk < k0 + 64; ++kk)
      acc = fmaf(sa[kk], w3[kk * 64 + c], acc);
    sp[t] = acc;
  }
  __syncthreads();
  if (t < 64) {
    const float s = cb3[t] + sp[t] + sp[t + 64] + sp[t + 128] + sp[t + 192];
    sc3[t] = fmaxf(s, 0.f);
  }
  __syncthreads();
  if (t < 3) {
    float acc = cb4[t];
#pragma unroll
    for (int kk = 0; kk < 64; ++kk) acc = fmaf(sc3[kk], w4[kk * 3 + t], acc);
    slg[t] = acc;
  }
  __syncthreads();
  if (t == 0) {
    float m = fmaxf(slg[0], fmaxf(slg[1], slg[2]));
    float se = __expf(slg[0] - m) + __expf(slg[1] - m) + __expf(slg[2] - m);
    float lse = m + logf(se);
    out[r * 3 + 0] = slg[0] - lse;
    out[r * 3 + 1] = slg[1] - lse;
    out[r * 3 + 2] = slg[2] - lse;
  }
}

extern "C" void kernel_launch(void* const* d_in, const int* in_sizes, int n_in,
                              void* d_out, int out_size, void* d_ws, size_t ws_size,
                              hipStream_t stream) {
  const float* x    = (const float*)d_in[0];
  const float* w1c  = (const float*)d_in[1];
  const float* b1c  = (const float*)d_in[2];
  const float* g1   = (const float*)d_in[3];
  const float* bb1  = (const float*)d_in[4];
  const float* w2c  = (const float*)d_in[5];
  const float* b2c  = (const float*)d_in[6];
  const float* g2   = (const float*)d_in[7];
  const float* bb2  = (const float*)d_in[8];
  const float* w3c  = (const float*)d_in[9];
  const float* b3c  = (const float*)d_in[10];
  const float* g3   = (const float*)d_in[11];
  const float* bb3  = (const float*)d_in[12];
  const float* fcw  = (const float*)d_in[13];
  const float* fcb  = (const float*)d_in[14];
  const float* sw1  = (const float*)d_in[15];
  const float* sb1  = (const float*)d_in[16];
  const float* sw2  = (const float*)d_in[17];
  const float* sb2  = (const float*)d_in[18];
  const float* sw3  = (const float*)d_in[19];
  const float* sb3  = (const float*)d_in[20];
  const float* sw4  = (const float*)d_in[21];
  const float* sb4  = (const float*)d_in[22];
  const float* cw1  = (const float*)d_in[23];
  const float* cb1  = (const float*)d_in[24];
  const float* cw2  = (const float*)d_in[25];
  const float* cb2  = (const float*)d_in[26];
  const float* cw3  = (const float*)d_in[27];
  const float* cb3  = (const float*)d_in[28];
  const float* cw4  = (const float*)d_in[29];
  const float* cb4  = (const float*)d_in[30];

  float* ws = (float*)d_ws;
  float* Ga       = ws;                  // 129600
  float* Gb       = ws + 129600;         // -> 259200
  float* subjects = ws + 259200;         // -> 530550
  float* part     = ws + 530560;         // 30*64*1024 -> 2496640
  float* bgagb    = ws + 2496640;        // 64 -> 2496704
  float* act1     = ws + 2496704;        // 30720 -> 2527424
  float* act2     = ws + 2527424;        // 7680 -> 2535104
  unsigned short* wsu = (unsigned short*)(ws + 2535104);
  unsigned short* w2frag  = wsu;               // 4096 sh
  unsigned short* w3frag  = wsu + 4096;        // 9216 sh
  unsigned short* bfragGG = wsu + 13312;       // 139264 sh
  unsigned short* act3    = wsu + 152576;      // 4050*2176 = 8812800 sh

  prep_kernel<<<75, 256, 0, stream>>>(w2c, g2, w3c, g3, fcw, fcb, sw1, sb1,
                                      w2frag, w3frag, bfragGG, bgagb);
  fe_kernel<<<2025, 128, 0, stream>>>(x, w1c, b1c, g1, bb1, b2c, g2, bb2,
                                      b3c, g3, bb3, w2frag, w3frag, act3);
  gagb_kernel<<<64, 256, 0, stream>>>(act3, bfragGG, bgagb, Ga, Gb);
  sim_kernel<<<480, 256, 0, stream>>>(Ga, Gb, sw2, sb2, sw3, sb3, sw4, sb4, subjects);
  c1_kernel<<<512, 256, 0, stream>>>(subjects, cw1, part);
  tail_a_kernel<<<120, 256, 0, stream>>>(part, cb1, act1);
  tail_b_kernel<<<240, 256, 0, stream>>>(act1, cw2, cb2, act2);
  tail_c_kernel<<<30, 256, 0, stream>>>(act2, cw3, cb3, cw4, cb4, (float*)d_out);
}

// Round 9
// 296.321 us; speedup vs baseline: 1.2564x; 1.1385x over previous
//
#include <hip/hip_runtime.h>
#include <math.h>

#define BN_SCALE 0.99999500003749967f
#define RRELU_SLOPE 0.22916666666666666f

static __device__ __forceinline__ float leaky(float v) { return v > 0.f ? v : 0.01f * v; }

typedef __attribute__((ext_vector_type(8))) short bf16x8;
typedef __attribute__((ext_vector_type(4))) float f32x4;

static __device__ __forceinline__ unsigned short f2bf(float f) {
  unsigned u = __builtin_bit_cast(unsigned, f);
  u = (u + 0x7FFFu + ((u >> 16) & 1u)) >> 16;
  return (unsigned short)u;
}

// ---------------------------------------------------------------------------
// prep: conv2/conv3 A-frags (bn-folded bf16), Wgagb = fcw @ [W1a|W1b] B-frags,
// folded biases, and zero-fill of the subjectsA fragment buffer (pads).
// ---------------------------------------------------------------------------
__global__ __launch_bounds__(256) void prep_kernel(
    const float* __restrict__ w2c, const float* __restrict__ g2,
    const float* __restrict__ w3c, const float* __restrict__ g3,
    const float* __restrict__ fcw, const float* __restrict__ fcb,
    const float* __restrict__ w1,  const float* __restrict__ b1,
    unsigned short* __restrict__ w2frag,
    unsigned short* __restrict__ w3frag,
    unsigned short* __restrict__ bfragGG,
    float* __restrict__ bgagb,
    unsigned short* __restrict__ subjectsA)
{
  const int item = blockIdx.x * 256 + threadIdx.x;
  if (item < 512) {                      // conv2 A-frags
    const int tile = item >> 6, lane = item & 63;
    const int mt = tile >> 1, kc = tile & 1;
    const int lr = lane & 15, quad = lane >> 4;
    const int c = mt * 16 + lr;
    const float gs = g2[c] * BN_SCALE;
#pragma unroll
    for (int j = 0; j < 8; ++j) {
      const int k = quad * 8 + j;
      float v;
      if (kc == 0) { const int tap = k >> 4, ci = k & 15; v = w2c[c * 48 + ci * 3 + tap] * gs; }
      else         { v = (k < 16) ? w2c[c * 48 + k * 3 + 2] * gs : 0.f; }
      w2frag[item * 8 + j] = f2bf(v);
    }
  } else if (item < 1664) {              // conv3 A-frags
    const int it = item - 512;
    const int tile = it >> 6, lane = it & 63;
    const int mt = tile / 3, tap = tile - mt * 3;
    const int lr = lane & 15, quad = lane >> 4;
    const int c = mt * 16 + lr;
    const float gs = g3[c] * BN_SCALE;
#pragma unroll
    for (int j = 0; j < 8; ++j) {
      const int ci = quad * 8 + j;
      w3frag[it * 8 + j] = f2bf(w3c[c * 96 + ci * 3 + tap] * gs);
    }
  } else if (item < 19072) {             // Wgagb B-frags
    const int it = item - 1664;
    const int chunk = it >> 8;
    const int rem = it & 255;
    const int nt = rem >> 6;
    const int lane = rem & 63;
    const int lr = lane & 15, quad = lane >> 4;
    const int n = nt * 16 + lr;
    const int off = (n >= 32) ? 32 : 0;
    const int nj = n & 31;
    float w1col[32];
#pragma unroll 8
    for (int q = 0; q < 32; ++q) w1col[q] = w1[(q + off) * 32 + nj];
#pragma unroll
    for (int j = 0; j < 8; ++j) {
      const int k = chunk * 32 + quad * 8 + j;
      float v = 0.f;
      if (k < 2160) {
        const float* fr = fcw + (size_t)k * 32;
#pragma unroll 8
        for (int q = 0; q < 32; ++q) v = fmaf(fr[q], w1col[q], v);
      }
      bfragGG[(size_t)it * 8 + j] = f2bf(v);
    }
  } else if (item < 19136) {             // folded biases
    const int n = item - 19072;
    const int off = (n >= 32) ? 32 : 0;
    const int nj = n & 31;
    float s = (n < 32) ? b1[nj] : 0.f;
    for (int q = 0; q < 32; ++q) s = fmaf(fcb[q], w1[(q + off) * 32 + nj], s);
    bgagb[n] = s;
  } else if (item < 55360) {             // zero subjectsA (283*1024 shorts)
    const int idx = item - 19136;
    uint4 z = {0u, 0u, 0u, 0u};
    ((uint4*)subjectsA)[idx] = z;
  }
}

// ---------------------------------------------------------------------------
// w1t: w1 (9045x1024 fp32) -> w1T (1024 x 9088 bf16), tiled LDS transpose.
// Rows of w1T are output columns, k-contiguous (single-load MFMA B-frags).
// ---------------------------------------------------------------------------
__global__ __launch_bounds__(256) void w1t_kernel(
    const float* __restrict__ w1, unsigned short* __restrict__ w1T)
{
  __shared__ float tile[64][65];
  const int kt = blockIdx.x >> 4;        // 0..141
  const int ntb = blockIdx.x & 15;
  const int k0 = kt * 64, n0 = ntb * 64;
  const int t = threadIdx.x;
#pragma unroll 4
  for (int i = 0; i < 16; ++i) {
    const int idx = i * 256 + t;
    const int kk = idx >> 6, nn = idx & 63;
    const int k = k0 + kk;
    tile[kk][nn] = (k < 9045) ? w1[(size_t)k * 1024 + n0 + nn] : 0.f;
  }
  __syncthreads();
#pragma unroll 4
  for (int i = 0; i < 8; ++i) {
    const int idx = i * 256 + t;
    const int nn = idx >> 5;             // 0..63
    const int kp = (idx & 31) * 2;       // even k within tile
    const unsigned lo = f2bf(tile[kp][nn]);
    const unsigned hi = f2bf(tile[kp + 1][nn]);
    ((unsigned*)w1T)[(size_t)(n0 + nn) * 4544 + (k0 >> 1) + (idx & 31)] = lo | (hi << 16);
  }
}

// ---------------------------------------------------------------------------
// fe: wave-autonomous, no barriers. 1 wave = 1 sequence; block=128.
// ---------------------------------------------------------------------------
__global__ __launch_bounds__(128) void fe_kernel(
    const float* __restrict__ x,
    const float* __restrict__ w1c, const float* __restrict__ b1c,
    const float* __restrict__ g1,  const float* __restrict__ bb1,
    const float* __restrict__ b2c, const float* __restrict__ g2, const float* __restrict__ bb2,
    const float* __restrict__ b3c, const float* __restrict__ g3, const float* __restrict__ bb3,
    const unsigned short* __restrict__ w2frag,
    const unsigned short* __restrict__ w3frag,
    unsigned short* __restrict__ act3)
{
  __shared__ __align__(16) char smem[2 * 13120];
  const int t = threadIdx.x;
  const int wv = t >> 6, lane = t & 63, quad = lane >> 4, lr = lane & 15;
  const int n = blockIdx.x * 2 + wv;

  char* A = smem + wv * 13120;
  unsigned short* s1t = (unsigned short*)A;
  unsigned short* s2t = (unsigned short*)(A + 6208);
  float* be2 = (float*)(A + 12480);
  float* be3 = (float*)(A + 12736);

  bf16x8 a2[4][2];
#pragma unroll
  for (int mt = 0; mt < 4; ++mt)
#pragma unroll
    for (int kc = 0; kc < 2; ++kc)
      a2[mt][kc] = *(const bf16x8*)(w2frag + ((mt * 2 + kc) * 64 + lane) * 8);

  be2[lane] = b2c[lane] * (g2[lane] * BN_SCALE) + bb2[lane];
  be3[lane] = b3c[lane] * (g3[lane] * BN_SCALE) + bb3[lane];
  if (lane < 32) be3[64 + lane] = b3c[64 + lane] * (g3[64 + lane] * BN_SCALE) + bb3[64 + lane];
  ((unsigned*)s1t)[186 * 8 + lane] = 0;
  ((unsigned*)s2t)[92 * 16 + lane] = 0;
  if (lane < 32) ((unsigned*)s2t)[92 * 16 + 64 + lane] = 0;

  const int cp = lane & 7;
  float u[4][3], bbr[4];
#pragma unroll
  for (int d = 0; d < 4; ++d) {
    const int c = cp * 4 + d;
    const float gs = g1[c] * BN_SCALE;
    u[d][0] = w1c[c * 3 + 0] * gs;
    u[d][1] = w1c[c * 3 + 1] * gs;
    u[d][2] = w1c[c * 3 + 2] * gs;
    bbr[d] = b1c[c] * gs + bb1[c];
  }

  const float* xr = x + (size_t)n * 375;
  for (int o = lane; o < 1488; o += 64) {
    const int l = o >> 3;
    const int p = 2 * l;
    const float x0 = xr[p], x1 = xr[p + 1], x2 = xr[p + 2], x3 = xr[p + 3];
    unsigned pk = 0;
#pragma unroll
    for (int uu = 0; uu < 2; ++uu) {
      float m = -3.4e38f;
#pragma unroll
      for (int dc = 0; dc < 2; ++dc) {
        const int d = uu * 2 + dc;
        const float v0 = fmaf(x0, u[d][0], fmaf(x1, u[d][1], fmaf(x2, u[d][2], bbr[d])));
        const float v1 = fmaf(x1, u[d][0], fmaf(x2, u[d][1], fmaf(x3, u[d][2], bbr[d])));
        m = fmaxf(m, fmaxf(leaky(v0), leaky(v1)));
      }
      pk |= (unsigned)f2bf(m) << (16 * uu);
    }
    ((unsigned*)s1t)[l * 8 + cp] = pk;
  }

  float be2r[4][4];
#pragma unroll
  for (int mt = 0; mt < 4; ++mt)
#pragma unroll
    for (int r = 0; r < 4; ++r) be2r[mt][r] = be2[mt * 16 + quad * 4 + r];

#pragma unroll 2
  for (int nt = 0; nt < 12; ++nt) {
    const int nrow = nt * 16 + lr;
    bf16x8 b0 = *(const bf16x8*)(s1t + (nrow + (quad >> 1)) * 16 + (quad & 1) * 8);
    bf16x8 b1 = *(const bf16x8*)(s1t + (nrow + 2) * 16 + (quad & 1) * 8);
    f32x4 acc[4];
#pragma unroll
    for (int mt = 0; mt < 4; ++mt)
#pragma unroll
      for (int r = 0; r < 4; ++r) acc[mt][r] = be2r[mt][r];
#pragma unroll
    for (int mt = 0; mt < 4; ++mt)
      acc[mt] = __builtin_amdgcn_mfma_f32_16x16x32_bf16(a2[mt][0], b0, acc[mt], 0, 0, 0);
#pragma unroll
    for (int mt = 0; mt < 4; ++mt)
      acc[mt] = __builtin_amdgcn_mfma_f32_16x16x32_bf16(a2[mt][1], b1, acc[mt], 0, 0, 0);
#pragma unroll
    for (int mt = 0; mt < 4; ++mt) {
      float o[4];
#pragma unroll
      for (int r = 0; r < 4; ++r) {
        const float v = leaky(acc[mt][r]);
        o[r] = fmaxf(v, __shfl_xor(v, 1));
      }
      if ((lr & 1) == 0) {
        const int np = nrow >> 1;
        if (np <= 91) {
          const float m0 = fmaxf(o[0], o[1]);
          const float m1 = fmaxf(o[2], o[3]);
          const unsigned pk = (unsigned)f2bf(m0) | ((unsigned)f2bf(m1) << 16);
          ((unsigned*)s2t)[np * 16 + mt * 4 + quad] = pk;
        }
      }
    }
  }

  unsigned short* actr = act3 + (size_t)n * 2176;
  for (int mt = 0; mt < 6; ++mt) {
    bf16x8 a3[3];
#pragma unroll
    for (int tap = 0; tap < 3; ++tap)
      a3[tap] = *(const bf16x8*)(w3frag + ((mt * 3 + tap) * 64 + lane) * 8);
    float be3r[4];
#pragma unroll
    for (int r = 0; r < 4; ++r) be3r[r] = be3[mt * 16 + quad * 4 + r];
#pragma unroll
    for (int nt = 0; nt < 6; ++nt) {
      const int nrow = nt * 16 + lr;
      f32x4 acc;
#pragma unroll
      for (int r = 0; r < 4; ++r) acc[r] = be3r[r];
#pragma unroll
      for (int tap = 0; tap < 3; ++tap) {
        bf16x8 b = *(const bf16x8*)(s2t + (nrow + tap) * 32 + quad * 8);
        acc = __builtin_amdgcn_mfma_f32_16x16x32_bf16(a3[tap], b, acc, 0, 0, 0);
      }
      float o[4];
#pragma unroll
      for (int r = 0; r < 4; ++r) {
        const float v = leaky(acc[r]);
        o[r] = fmaxf(v, __shfl_xor(v, 1));
      }
      if ((lr & 1) == 0) {
        const int np = nrow >> 1;
        if (np <= 44) {
          const int mp = mt * 8 + quad * 2;
          actr[mp * 45 + np] = f2bf(fmaxf(o[0], o[1]));
          actr[(mp + 1) * 45 + np] = f2bf(fmaxf(o[2], o[3]));
        }
      }
    }
  }
  if (lane < 16) actr[2160 + lane] = 0;
}

// ---------------------------------------------------------------------------
// gagb: [Ga|Gb](4050x64) = act3 @ Wgagb + bgagb via MFMA.
// ---------------------------------------------------------------------------
__global__ __launch_bounds__(256) void gagb_kernel(
    const unsigned short* __restrict__ act3,
    const unsigned short* __restrict__ bfragGG,
    const float* __restrict__ bgagb,
    float* __restrict__ Ga, float* __restrict__ Gb)
{
  const int t = threadIdx.x;
  const int wv = t >> 6, lane = t & 63, quad = lane >> 4, lr = lane & 15;
  const int m0 = blockIdx.x * 64 + wv * 16;
  const int arow = min(m0 + lr, 4049);

  f32x4 acc[4] = {};
  for (int chunk = 0; chunk < 68; ++chunk) {
    const bf16x8 a = *(const bf16x8*)(act3 + (size_t)arow * 2176 + chunk * 32 + quad * 8);
#pragma unroll
    for (int nt = 0; nt < 4; ++nt) {
      const bf16x8 b = *(const bf16x8*)(bfragGG + ((size_t)(chunk * 4 + nt) * 64 + lane) * 8);
      acc[nt] = __builtin_amdgcn_mfma_f32_16x16x32_bf16(a, b, acc[nt], 0, 0, 0);
    }
  }
#pragma unroll
  for (int nt = 0; nt < 4; ++nt) {
    const int col = nt * 16 + lr;
    const float bias = bgagb[col];
#pragma unroll
    for (int r = 0; r < 4; ++r) {
      const int row = m0 + quad * 4 + r;
      if (row < 4050) {
        const float v = acc[nt][r] + bias;
        if (col < 32) Ga[row * 32 + col] = v;
        else          Gb[row * 32 + (col - 32)] = v;
      }
    }
  }
}

// ---------------------------------------------------------------------------
// sim: writes bf16 MFMA A-fragments of the subjects matrix (30 x 9045).
// ---------------------------------------------------------------------------
__global__ __launch_bounds__(256) void sim_kernel(
    const float* __restrict__ Ga, const float* __restrict__ Gb,
    const float* __restrict__ w2, const float* __restrict__ b2,
    const float* __restrict__ w3, const float* __restrict__ b3,
    const float* __restrict__ w4, const float* __restrict__ b4,
    unsigned short* __restrict__ subjectsA)
{
  __shared__ float sGa[135 * 36];
  __shared__ float sGb[135 * 36];
  __shared__ float sw2[512], sw3[128], sw4[8];
  __shared__ float sb2[16], sb3[8], sb4v[1];

  const int t = threadIdx.x;
  const int b = blockIdx.x >> 4;
  const int c = blockIdx.x & 15;

  for (int i = t; i < 4320; i += 256) {
    const int r = i >> 5, col = i & 31;
    sGa[r * 36 + col] = Ga[b * 4320 + i];
    sGb[r * 36 + col] = Gb[b * 4320 + i];
  }
  for (int i = t; i < 512; i += 256) sw2[i] = w2[i];
  if (t < 128) sw3[t] = w3[t];
  if (t < 8) sw4[t] = w4[t];
  if (t < 16) sb2[t] = b2[t];
  if (t < 8) sb3[t] = b3[t];
  if (t == 0) sb4v[0] = b4[0];
  __syncthreads();

  const int mtile = b >> 4, lrm = b & 15;
  const int pend = min(9045, (c + 1) * 566);
  for (int p = c * 566 + t; p < pend; p += 256) {
    int i = (int)((269.0f - sqrtf((float)(72361 - 8 * p))) * 0.5f);
    i = max(0, min(133, i));
    while (134 * (i + 1) - ((i + 1) * i) / 2 <= p) ++i;
    while (134 * i - (i * (i - 1)) / 2 > p) --i;
    const int j = i + 1 + (p - (134 * i - (i * (i - 1)) / 2));

    float h1[32];
#pragma unroll
    for (int q = 0; q < 8; ++q) {
      const float4 va = *(const float4*)(&sGa[i * 36 + 4 * q]);
      const float4 vb = *(const float4*)(&sGb[j * 36 + 4 * q]);
      h1[4 * q + 0] = fmaxf(va.x + vb.x, 0.f);
      h1[4 * q + 1] = fmaxf(va.y + vb.y, 0.f);
      h1[4 * q + 2] = fmaxf(va.z + vb.z, 0.f);
      h1[4 * q + 3] = fmaxf(va.w + vb.w, 0.f);
    }

    float h2[16];
#pragma unroll
    for (int jj = 0; jj < 16; ++jj) h2[jj] = sb2[jj];
#pragma unroll 8
    for (int ii = 0; ii < 32; ++ii) {
      const float av = h1[ii];
      const float4* wr = reinterpret_cast<const float4*>(&sw2[ii * 16]);
#pragma unroll
      for (int r = 0; r < 4; ++r) {
        float4 w = wr[r];
        h2[4 * r + 0] = fmaf(av, w.x, h2[4 * r + 0]);
        h2[4 * r + 1] = fmaf(av, w.y, h2[4 * r + 1]);
        h2[4 * r + 2] = fmaf(av, w.z, h2[4 * r + 2]);
        h2[4 * r + 3] = fmaf(av, w.w, h2[4 * r + 3]);
      }
    }
#pragma unroll
    for (int jj = 0; jj < 16; ++jj) h2[jj] = fmaxf(h2[jj], 0.f);

    float h3[8];
#pragma unroll
    for (int jj = 0; jj < 8; ++jj) h3[jj] = sb3[jj];
#pragma unroll
    for (int ii = 0; ii < 16; ++ii) {
      const float av = h2[ii];
      const float4* wr = reinterpret_cast<const float4*>(&sw3[ii * 8]);
#pragma unroll
      for (int r = 0; r < 2; ++r) {
        float4 w = wr[r];
        h3[4 * r + 0] = fmaf(av, w.x, h3[4 * r + 0]);
        h3[4 * r + 1] = fmaf(av, w.y, h3[4 * r + 1]);
        h3[4 * r + 2] = fmaf(av, w.z, h3[4 * r + 2]);
        h3[4 * r + 3] = fmaf(av, w.w, h3[4 * r + 3]);
      }
    }
#pragma unroll
    for (int jj = 0; jj < 8; ++jj) h3[jj] = fmaxf(h3[jj], 0.f);

    float z = sb4v[0];
#pragma unroll
    for (int ii = 0; ii < 8; ++ii) z = fmaf(h3[ii], sw4[ii], z);

    const float az = fabsf(z);
    const float e = __expf(-2.f * az);
    const float rr = (1.f - e) / (1.f + e);
    const float val = copysignf(rr, z);

    // A-fragment store: chunk=p>>5, quad=(p&31)>>3, j=p&7, lane=quad*16+(b&15)
    const int chunk = p >> 5, q8 = (p & 31) >> 3, jj2 = p & 7;
    subjectsA[chunk * 1024 + mtile * 512 + (q8 * 16 + lrm) * 8 + jj2] = f2bf(val);
  }
}

// ---------------------------------------------------------------------------
// c1 (MFMA): C(30x1024) = subjects @ w1. 256 blocks x 4 waves = 1024 jobs
// (16 n-groups x 64 k-groups of 5 chunks). Partials [m][kg][1024].
// ---------------------------------------------------------------------------
__global__ __launch_bounds__(256) void c1_kernel(
    const unsigned short* __restrict__ subjectsA,
    const unsigned short* __restrict__ w1T,
    float* __restrict__ part)
{
  const int t = threadIdx.x;
  const int wv = t >> 6, lane = t & 63, quad = lane >> 4, lr = lane & 15;
  const int job = blockIdx.x * 4 + wv;
  const int ng = job & 15;
  const int kg = job >> 4;
  const int c0 = kg * 5;
  const int cend = min(283, c0 + 5);

  f32x4 acc[2][4] = {};
  for (int ch = c0; ch < cend; ++ch) {
    const bf16x8 a0 = *(const bf16x8*)(subjectsA + ch * 1024 + lane * 8);
    const bf16x8 a1 = *(const bf16x8*)(subjectsA + ch * 1024 + 512 + lane * 8);
#pragma unroll
    for (int nt = 0; nt < 4; ++nt) {
      const int col = (ng * 4 + nt) * 16 + lr;
      const bf16x8 b = *(const bf16x8*)(w1T + (size_t)col * 9088 + ch * 32 + quad * 8);
      acc[0][nt] = __builtin_amdgcn_mfma_f32_16x16x32_bf16(a0, b, acc[0][nt], 0, 0, 0);
      acc[1][nt] = __builtin_amdgcn_mfma_f32_16x16x32_bf16(a1, b, acc[1][nt], 0, 0, 0);
    }
  }
#pragma unroll
  for (int mt = 0; mt < 2; ++mt)
#pragma unroll
    for (int r = 0; r < 4; ++r) {
      const int m = mt * 16 + quad * 4 + r;
      if (m < 30) {
#pragma unroll
        for (int nt = 0; nt < 4; ++nt) {
          const int col = (ng * 4 + nt) * 16 + lr;
          part[(size_t)(m * 64 + kg) * 1024 + col] = acc[mt][nt][r];
        }
      }
    }
}

// ---------------------------------------------------------------------------
// tail_a: reduce 64 partials + rrelu -> act1[30][1024]. 120 blocks.
// ---------------------------------------------------------------------------
__global__ __launch_bounds__(256) void tail_a_kernel(
    const float* __restrict__ part,
    const float* __restrict__ cb1,
    float* __restrict__ act1)
{
  const int r = blockIdx.x >> 2;
  const int cg = blockIdx.x & 3;
  const int j = cg * 256 + threadIdx.x;
  float s = cb1[j];
  const float* pp = part + (size_t)r * 64 * 1024 + j;
#pragma unroll 8
  for (int q = 0; q < 64; ++q) s += pp[q * 1024];
  act1[r * 1024 + j] = s >= 0.f ? s : RRELU_SLOPE * s;
}

// ---------------------------------------------------------------------------
// tail_b: GEMM2 (1024->256) + relu -> act2. 240 blocks.
// ---------------------------------------------------------------------------
__global__ __launch_bounds__(256) void tail_b_kernel(
    const float* __restrict__ act1,
    const float* __restrict__ w2, const float* __restrict__ cb2,
    float* __restrict__ act2)
{
  __shared__ float sa[1024];
  __shared__ float sp[256];
  const int r = blockIdx.x >> 3;
  const int cg = blockIdx.x & 7;
  const int t = threadIdx.x;
  const int c = t & 31;
  const int ks = t >> 5;
  const int col = cg * 32 + c;

  for (int i = t; i < 1024; i += 256) sa[i] = act1[r * 1024 + i];
  __syncthreads();

  float acc = 0.f;
  const int k0 = ks * 128;
  for (int kk = k0; kk < k0 + 128; kk += 4) {
    const float4 a = *reinterpret_cast<const float4*>(&sa[kk]);
    acc = fmaf(a.x, w2[(kk + 0) * 256 + col], acc);
    acc = fmaf(a.y, w2[(kk + 1) * 256 + col], acc);
    acc = fmaf(a.z, w2[(kk + 2) * 256 + col], acc);
    acc = fmaf(a.w, w2[(kk + 3) * 256 + col], acc);
  }
  sp[t] = acc;
  __syncthreads();
  if (t < 32) {
    float s = cb2[col];
#pragma unroll
    for (int q = 0; q < 8; ++q) s += sp[q * 32 + t];
    act2[r * 256 + cg * 32 + t] = fmaxf(s, 0.f);
  }
}

// ---------------------------------------------------------------------------
// tail_c: GEMM3 (256->64, 4-way k-split) + GEMM4 (64->3) + log_softmax.
// ---------------------------------------------------------------------------
__global__ __launch_bounds__(256) void tail_c_kernel(
    const float* __restrict__ act2,
    const float* __restrict__ w3, const float* __restrict__ cb3,
    const float* __restrict__ w4, const float* __restrict__ cb4,
    float* __restrict__ out)
{
  __shared__ float sa[256];
  __shared__ float sp[256];
  __shared__ float sc3[64];
  __shared__ float slg[3];
  const int r = blockIdx.x, t = threadIdx.x;
  const int c = t & 63;
  const int ks = t >> 6;

  sa[t] = act2[r * 256 + t];
  __syncthreads();
  {
    float acc = 0.f;
    const int k0 = ks * 64;
#pragma unroll 4
    for (int kk = k0; kk < k0 + 64; ++kk)
      acc = fmaf(sa[kk], w3[kk * 64 + c], acc);
    sp[t] = acc;
  }
  __syncthreads();
  if (t < 64) {
    const float s = cb3[t] + sp[t] + sp[t + 64] + sp[t + 128] + sp[t + 192];
    sc3[t] = fmaxf(s, 0.f);
  }
  __syncthreads();
  if (t < 3) {
    float acc = cb4[t];
#pragma unroll
    for (int kk = 0; kk < 64; ++kk) acc = fmaf(sc3[kk], w4[kk * 3 + t], acc);
    slg[t] = acc;
  }
  __syncthreads();
  if (t == 0) {
    float m = fmaxf(slg[0], fmaxf(slg[1], slg[2]));
    float se = __expf(slg[0] - m) + __expf(slg[1] - m) + __expf(slg[2] - m);
    float lse = m + logf(se);
    out[r * 3 + 0] = slg[0] - lse;
    out[r * 3 + 1] = slg[1] - lse;
    out[r * 3 + 2] = slg[2] - lse;
  }
}

extern "C" void kernel_launch(void* const* d_in, const int* in_sizes, int n_in,
                              void* d_out, int out_size, void* d_ws, size_t ws_size,
                              hipStream_t stream) {
  const float* x    = (const float*)d_in[0];
  const float* w1c  = (const float*)d_in[1];
  const float* b1c  = (const float*)d_in[2];
  const float* g1   = (const float*)d_in[3];
  const float* bb1  = (const float*)d_in[4];
  const float* w2c  = (const float*)d_in[5];
  const float* b2c  = (const float*)d_in[6];
  const float* g2   = (const float*)d_in[7];
  const float* bb2  = (const float*)d_in[8];
  const float* w3c  = (const float*)d_in[9];
  const float* b3c  = (const float*)d_in[10];
  const float* g3   = (const float*)d_in[11];
  const float* bb3  = (const float*)d_in[12];
  const float* fcw  = (const float*)d_in[13];
  const float* fcb  = (const float*)d_in[14];
  const float* sw1  = (const float*)d_in[15];
  const float* sb1  = (const float*)d_in[16];
  const float* sw2  = (const float*)d_in[17];
  const float* sb2  = (const float*)d_in[18];
  const float* sw3  = (const float*)d_in[19];
  const float* sb3  = (const float*)d_in[20];
  const float* sw4  = (const float*)d_in[21];
  const float* sb4  = (const float*)d_in[22];
  const float* cw1  = (const float*)d_in[23];
  const float* cb1  = (const float*)d_in[24];
  const float* cw2  = (const float*)d_in[25];
  const float* cb2  = (const float*)d_in[26];
  const float* cw3  = (const float*)d_in[27];
  const float* cb3  = (const float*)d_in[28];
  const float* cw4  = (const float*)d_in[29];
  const float* cb4  = (const float*)d_in[30];

  float* ws = (float*)d_ws;
  float* Ga    = ws;                     // 129600
  float* Gb    = ws + 129600;            // -> 259200
  float* part  = ws + 259200;            // 30*64*1024 -> 2225280
  float* bgagb = ws + 2225280;           // 64 -> 2225344
  float* act1  = ws + 2225344;           // 30720 -> 2256064
  float* act2  = ws + 2256064;           // 7680 -> 2263744
  unsigned short* wsu = (unsigned short*)(ws + 2263744);
  unsigned short* w2frag    = wsu;             // 4096 sh
  unsigned short* w3frag    = wsu + 4096;      // 9216 sh -> 13312
  unsigned short* bfragGG   = wsu + 13312;     // 139264 sh -> 152576
  unsigned short* act3      = wsu + 152576;    // 8812800 sh -> 8965376
  unsigned short* subjectsA = wsu + 8965376;   // 289792 sh -> 9255168
  unsigned short* w1T       = wsu + 9255168;   // 1024*9088 = 9306112 sh

  prep_kernel<<<217, 256, 0, stream>>>(w2c, g2, w3c, g3, fcw, fcb, sw1, sb1,
                                       w2frag, w3frag, bfragGG, bgagb, subjectsA);
  w1t_kernel<<<2272, 256, 0, stream>>>(cw1, w1T);
  fe_kernel<<<2025, 128, 0, stream>>>(x, w1c, b1c, g1, bb1, b2c, g2, bb2,
                                      b3c, g3, bb3, w2frag, w3frag, act3);
  gagb_kernel<<<64, 256, 0, stream>>>(act3, bfragGG, bgagb, Ga, Gb);
  sim_kernel<<<480, 256, 0, stream>>>(Ga, Gb, sw2, sb2, sw3, sb3, sw4, sb4, subjectsA);
  c1_kernel<<<256, 256, 0, stream>>>(subjectsA, w1T, part);
  tail_a_kernel<<<120, 256, 0, stream>>>(part, cb1, act1);
  tail_b_kernel<<<240, 256, 0, stream>>>(act1, cw2, cb2, act2);
  tail_c_kernel<<<30, 256, 0, stream>>>(act2, cw3, cb3, cw4, cb4, (float*)d_out);
}

// Round 10
// 270.509 us; speedup vs baseline: 1.3763x; 1.0954x over previous
//
#include <hip/hip_runtime.h>
#include <math.h>

#define BN_SCALE 0.99999500003749967f
#define RRELU_SLOPE 0.22916666666666666f

static __device__ __forceinline__ float leaky(float v) { return v > 0.f ? v : 0.01f * v; }

typedef __attribute__((ext_vector_type(8))) short bf16x8;
typedef __attribute__((ext_vector_type(4))) float f32x4;

static __device__ __forceinline__ unsigned short f2bf(float f) {
  unsigned u = __builtin_bit_cast(unsigned, f);
  u = (u + 0x7FFFu + ((u >> 16) & 1u)) >> 16;
  return (unsigned short)u;
}

// ---------------------------------------------------------------------------
// setup (merged prep + w1t): blocks 0..2271 transpose w1 -> w1T bf16;
// blocks 2272.. do conv frags, Wgagb B-frags, folded biases, subjectsA zero.
// ---------------------------------------------------------------------------
__global__ __launch_bounds__(256) void setup_kernel(
    const float* __restrict__ w2c, const float* __restrict__ g2,
    const float* __restrict__ w3c, const float* __restrict__ g3,
    const float* __restrict__ fcw, const float* __restrict__ fcb,
    const float* __restrict__ w1,  const float* __restrict__ b1,
    const float* __restrict__ cw1,
    unsigned short* __restrict__ w2frag,
    unsigned short* __restrict__ w3frag,
    unsigned short* __restrict__ bfragGG,
    float* __restrict__ bgagb,
    unsigned short* __restrict__ subjectsA,
    unsigned short* __restrict__ w1T)
{
  __shared__ float tile[64][65];
  const int t = threadIdx.x;
  if (blockIdx.x < 2272) {               // ---- w1 transpose -> w1T ----
    const int kt = blockIdx.x >> 4;
    const int ntb = blockIdx.x & 15;
    const int k0 = kt * 64, n0 = ntb * 64;
#pragma unroll 4
    for (int i = 0; i < 16; ++i) {
      const int idx = i * 256 + t;
      const int kk = idx >> 6, nn = idx & 63;
      const int k = k0 + kk;
      tile[kk][nn] = (k < 9045) ? cw1[(size_t)k * 1024 + n0 + nn] : 0.f;
    }
    __syncthreads();
#pragma unroll 4
    for (int i = 0; i < 8; ++i) {
      const int idx = i * 256 + t;
      const int nn = idx >> 5;
      const int kp = (idx & 31) * 2;
      const unsigned lo = f2bf(tile[kp][nn]);
      const unsigned hi = f2bf(tile[kp + 1][nn]);
      ((unsigned*)w1T)[(size_t)(n0 + nn) * 4544 + (k0 >> 1) + (idx & 31)] = lo | (hi << 16);
    }
    return;
  }
  const int item = (blockIdx.x - 2272) * 256 + t;
  if (item < 512) {                      // conv2 A-frags
    const int tl = item >> 6, lane = item & 63;
    const int mt = tl >> 1, kc = tl & 1;
    const int lr = lane & 15, quad = lane >> 4;
    const int c = mt * 16 + lr;
    const float gs = g2[c] * BN_SCALE;
#pragma unroll
    for (int j = 0; j < 8; ++j) {
      const int k = quad * 8 + j;
      float v;
      if (kc == 0) { const int tap = k >> 4, ci = k & 15; v = w2c[c * 48 + ci * 3 + tap] * gs; }
      else         { v = (k < 16) ? w2c[c * 48 + k * 3 + 2] * gs : 0.f; }
      w2frag[item * 8 + j] = f2bf(v);
    }
  } else if (item < 1664) {              // conv3 A-frags
    const int it = item - 512;
    const int tl = it >> 6, lane = it & 63;
    const int mt = tl / 3, tap = tl - mt * 3;
    const int lr = lane & 15, quad = lane >> 4;
    const int c = mt * 16 + lr;
    const float gs = g3[c] * BN_SCALE;
#pragma unroll
    for (int j = 0; j < 8; ++j) {
      const int ci = quad * 8 + j;
      w3frag[it * 8 + j] = f2bf(w3c[c * 96 + ci * 3 + tap] * gs);
    }
  } else if (item < 19072) {             // Wgagb B-frags
    const int it = item - 1664;
    const int chunk = it >> 8;
    const int rem = it & 255;
    const int nt = rem >> 6;
    const int lane = rem & 63;
    const int lr = lane & 15, quad = lane >> 4;
    const int n = nt * 16 + lr;
    const int off = (n >= 32) ? 32 : 0;
    const int nj = n & 31;
    float w1col[32];
#pragma unroll 8
    for (int q = 0; q < 32; ++q) w1col[q] = w1[(q + off) * 32 + nj];
#pragma unroll
    for (int j = 0; j < 8; ++j) {
      const int k = chunk * 32 + quad * 8 + j;
      float v = 0.f;
      if (k < 2160) {
        const float* fr = fcw + (size_t)k * 32;
#pragma unroll 8
        for (int q = 0; q < 32; ++q) v = fmaf(fr[q], w1col[q], v);
      }
      bfragGG[(size_t)it * 8 + j] = f2bf(v);
    }
  } else if (item < 19136) {             // folded biases
    const int n = item - 19072;
    const int off = (n >= 32) ? 32 : 0;
    const int nj = n & 31;
    float s = (n < 32) ? b1[nj] : 0.f;
    for (int q = 0; q < 32; ++q) s = fmaf(fcb[q], w1[(q + off) * 32 + nj], s);
    bgagb[n] = s;
  } else if (item < 55360) {             // zero subjectsA (283*1024 shorts)
    const int idx = item - 19136;
    uint4 z = {0u, 0u, 0u, 0u};
    ((uint4*)subjectsA)[idx] = z;
  }
}

// ---------------------------------------------------------------------------
// fe: wave-autonomous; s2t OVERLAYS s1t (safe: tile nt reads rows 16nt..16nt+17
// before writing rows <=16nt+15; later tiles read only higher rows; same
// pointer -> compiler keeps order; DS pipe in-order per wave). Arena 6912 B
// per wave -> 11 blocks (22 waves)/CU.
// ---------------------------------------------------------------------------
__global__ __launch_bounds__(128) void fe_kernel(
    const float* __restrict__ x,
    const float* __restrict__ w1c, const float* __restrict__ b1c,
    const float* __restrict__ g1,  const float* __restrict__ bb1,
    const float* __restrict__ b2c, const float* __restrict__ g2, const float* __restrict__ bb2,
    const float* __restrict__ b3c, const float* __restrict__ g3, const float* __restrict__ bb3,
    const unsigned short* __restrict__ w2frag,
    const unsigned short* __restrict__ w3frag,
    unsigned short* __restrict__ act3)
{
  __shared__ __align__(16) char smem[2 * 6912];
  const int t = threadIdx.x;
  const int wv = t >> 6, lane = t & 63, quad = lane >> 4, lr = lane & 15;
  const int n = blockIdx.x * 2 + wv;

  char* A = smem + wv * 6912;
  unsigned short* buf = (unsigned short*)A;   // s1t: 194r x 16sh / s2t: 98r x 32sh (overlaid)
  float* be2 = (float*)(A + 6272);            // 64
  float* be3 = (float*)(A + 6528);            // 96

  bf16x8 a2[4][2];
#pragma unroll
  for (int mt = 0; mt < 4; ++mt)
#pragma unroll
    for (int kc = 0; kc < 2; ++kc)
      a2[mt][kc] = *(const bf16x8*)(w2frag + ((mt * 2 + kc) * 64 + lane) * 8);

  be2[lane] = b2c[lane] * (g2[lane] * BN_SCALE) + bb2[lane];
  be3[lane] = b3c[lane] * (g3[lane] * BN_SCALE) + bb3[lane];
  if (lane < 32) be3[64 + lane] = b3c[64 + lane] * (g3[64 + lane] * BN_SCALE) + bb3[64 + lane];
  ((unsigned*)buf)[1488 + lane] = 0;          // s1t pad rows 186..193

  const int cp = lane & 7;
  float u[4][3], bbr[4];
#pragma unroll
  for (int d = 0; d < 4; ++d) {
    const int c = cp * 4 + d;
    const float gs = g1[c] * BN_SCALE;
    u[d][0] = w1c[c * 3 + 0] * gs;
    u[d][1] = w1c[c * 3 + 1] * gs;
    u[d][2] = w1c[c * 3 + 2] * gs;
    bbr[d] = b1c[c] * gs + bb1[c];
  }

  // ---- stage 1: conv1+bn+leaky+pool -> buf rows 0..185 (16sh stride) ----
  const float* xr = x + (size_t)n * 375;
  for (int o = lane; o < 1488; o += 64) {
    const int l = o >> 3;
    const int p = 2 * l;
    const float x0 = xr[p], x1 = xr[p + 1], x2 = xr[p + 2], x3 = xr[p + 3];
    unsigned pk = 0;
#pragma unroll
    for (int uu = 0; uu < 2; ++uu) {
      float m = -3.4e38f;
#pragma unroll
      for (int dc = 0; dc < 2; ++dc) {
        const int d = uu * 2 + dc;
        const float v0 = fmaf(x0, u[d][0], fmaf(x1, u[d][1], fmaf(x2, u[d][2], bbr[d])));
        const float v1 = fmaf(x1, u[d][0], fmaf(x2, u[d][1], fmaf(x3, u[d][2], bbr[d])));
        m = fmaxf(m, fmaxf(leaky(v0), leaky(v1)));
      }
      pk |= (unsigned)f2bf(m) << (16 * uu);
    }
    ((unsigned*)buf)[l * 8 + cp] = pk;
  }

  float be2r[4][4];
#pragma unroll
  for (int mt = 0; mt < 4; ++mt)
#pragma unroll
    for (int r = 0; r < 4; ++r) be2r[mt][r] = be2[mt * 16 + quad * 4 + r];

  // ---- conv2: 12 n-tiles; reads s1t rows, writes s2t rows (overlaid) ----
#pragma unroll 2
  for (int nt = 0; nt < 12; ++nt) {
    const int nrow = nt * 16 + lr;
    bf16x8 b0 = *(const bf16x8*)(buf + (nrow + (quad >> 1)) * 16 + (quad & 1) * 8);
    bf16x8 b1 = *(const bf16x8*)(buf + (nrow + 2) * 16 + (quad & 1) * 8);
    f32x4 acc[4];
#pragma unroll
    for (int mt = 0; mt < 4; ++mt)
#pragma unroll
      for (int r = 0; r < 4; ++r) acc[mt][r] = be2r[mt][r];
#pragma unroll
    for (int mt = 0; mt < 4; ++mt)
      acc[mt] = __builtin_amdgcn_mfma_f32_16x16x32_bf16(a2[mt][0], b0, acc[mt], 0, 0, 0);
#pragma unroll
    for (int mt = 0; mt < 4; ++mt)
      acc[mt] = __builtin_amdgcn_mfma_f32_16x16x32_bf16(a2[mt][1], b1, acc[mt], 0, 0, 0);
#pragma unroll
    for (int mt = 0; mt < 4; ++mt) {
      float o[4];
#pragma unroll
      for (int r = 0; r < 4; ++r) {
        const float v = leaky(acc[mt][r]);
        o[r] = fmaxf(v, __shfl_xor(v, 1));
      }
      if ((lr & 1) == 0) {
        const int np = nrow >> 1;
        if (np <= 91) {
          const float m0 = fmaxf(o[0], o[1]);
          const float m1 = fmaxf(o[2], o[3]);
          const unsigned pk = (unsigned)f2bf(m0) | ((unsigned)f2bf(m1) << 16);
          ((unsigned*)buf)[np * 16 + mt * 4 + quad] = pk;
        }
      }
    }
  }

  // ---- zero s2t pad rows 92..97 (safe: conv2 done with s1t tail) ----
  ((unsigned*)buf)[1472 + lane] = 0;
  if (lane < 32) ((unsigned*)buf)[1536 + lane] = 0;

  // ---- conv3: 6x6 tiles x 3 tap-MFMAs; epilogue -> act3 (global) ----
  unsigned short* actr = act3 + (size_t)n * 2176;
  for (int mt = 0; mt < 6; ++mt) {
    bf16x8 a3[3];
#pragma unroll
    for (int tap = 0; tap < 3; ++tap)
      a3[tap] = *(const bf16x8*)(w3frag + ((mt * 3 + tap) * 64 + lane) * 8);
    float be3r[4];
#pragma unroll
    for (int r = 0; r < 4; ++r) be3r[r] = be3[mt * 16 + quad * 4 + r];
#pragma unroll
    for (int nt = 0; nt < 6; ++nt) {
      const int nrow = nt * 16 + lr;
      f32x4 acc;
#pragma unroll
      for (int r = 0; r < 4; ++r) acc[r] = be3r[r];
#pragma unroll
      for (int tap = 0; tap < 3; ++tap) {
        bf16x8 b = *(const bf16x8*)(buf + (nrow + tap) * 32 + quad * 8);
        acc = __builtin_amdgcn_mfma_f32_16x16x32_bf16(a3[tap], b, acc, 0, 0, 0);
      }
      float o[4];
#pragma unroll
      for (int r = 0; r < 4; ++r) {
        const float v = leaky(acc[r]);
        o[r] = fmaxf(v, __shfl_xor(v, 1));
      }
      if ((lr & 1) == 0) {
        const int np = nrow >> 1;
        if (np <= 44) {
          const int mp = mt * 8 + quad * 2;
          actr[mp * 45 + np] = f2bf(fmaxf(o[0], o[1]));
          actr[(mp + 1) * 45 + np] = f2bf(fmaxf(o[2], o[3]));
        }
      }
    }
  }
  if (lane < 16) actr[2160 + lane] = 0;
}

// ---------------------------------------------------------------------------
// gagb: 254 blocks x 16 rows; 4 waves split K (17 chunks each); LDS reduce.
// ---------------------------------------------------------------------------
__global__ __launch_bounds__(256) void gagb_kernel(
    const unsigned short* __restrict__ act3,
    const unsigned short* __restrict__ bfragGG,
    const float* __restrict__ bgagb,
    float* __restrict__ Ga, float* __restrict__ Gb)
{
  __shared__ f32x4 sred[3][4][64];
  const int t = threadIdx.x;
  const int wv = t >> 6, lane = t & 63, quad = lane >> 4, lr = lane & 15;
  const int m0 = blockIdx.x * 16;
  const int arow = min(m0 + lr, 4049);

  f32x4 acc[4] = {};
  const int c0 = wv * 17;
  for (int chunk = c0; chunk < c0 + 17; ++chunk) {
    const bf16x8 a = *(const bf16x8*)(act3 + (size_t)arow * 2176 + chunk * 32 + quad * 8);
#pragma unroll
    for (int nt = 0; nt < 4; ++nt) {
      const bf16x8 b = *(const bf16x8*)(bfragGG + ((size_t)(chunk * 4 + nt) * 64 + lane) * 8);
      acc[nt] = __builtin_amdgcn_mfma_f32_16x16x32_bf16(a, b, acc[nt], 0, 0, 0);
    }
  }
  if (wv > 0) {
#pragma unroll
    for (int nt = 0; nt < 4; ++nt) sred[wv - 1][nt][lane] = acc[nt];
  }
  __syncthreads();
  if (wv == 0) {
#pragma unroll
    for (int nt = 0; nt < 4; ++nt) {
      f32x4 s = acc[nt];
#pragma unroll
      for (int q = 0; q < 3; ++q) {
        const f32x4 o = sred[q][nt][lane];
#pragma unroll
        for (int r = 0; r < 4; ++r) s[r] += o[r];
      }
      const int col = nt * 16 + lr;
      const float bias = bgagb[col];
#pragma unroll
      for (int r = 0; r < 4; ++r) {
        const int row = m0 + quad * 4 + r;
        if (row < 4050) {
          const float v = s[r] + bias;
          if (col < 32) Ga[row * 32 + col] = v;
          else          Gb[row * 32 + (col - 32)] = v;
        }
      }
    }
  }
}

// ---------------------------------------------------------------------------
// sim: 960 blocks = 30 subjects x 32 chunks; writes bf16 MFMA A-fragments.
// ---------------------------------------------------------------------------
__global__ __launch_bounds__(256) void sim_kernel(
    const float* __restrict__ Ga, const float* __restrict__ Gb,
    const float* __restrict__ w2, const float* __restrict__ b2,
    const float* __restrict__ w3, const float* __restrict__ b3,
    const float* __restrict__ w4, const float* __restrict__ b4,
    unsigned short* __restrict__ subjectsA)
{
  __shared__ float sGa[135 * 36];
  __shared__ float sGb[135 * 36];
  __shared__ float sw2[512], sw3[128], sw4[8];
  __shared__ float sb2[16], sb3[8], sb4v[1];

  const int t = threadIdx.x;
  const int b = blockIdx.x >> 5;
  const int c = blockIdx.x & 31;

  for (int i = t; i < 4320; i += 256) {
    const int r = i >> 5, col = i & 31;
    sGa[r * 36 + col] = Ga[b * 4320 + i];
    sGb[r * 36 + col] = Gb[b * 4320 + i];
  }
  for (int i = t; i < 512; i += 256) sw2[i] = w2[i];
  if (t < 128) sw3[t] = w3[t];
  if (t < 8) sw4[t] = w4[t];
  if (t < 16) sb2[t] = b2[t];
  if (t < 8) sb3[t] = b3[t];
  if (t == 0) sb4v[0] = b4[0];
  __syncthreads();

  const int mtile = b >> 4, lrm = b & 15;
  const int pend = min(9045, (c + 1) * 283);
  for (int p = c * 283 + t; p < pend; p += 256) {
    int i = (int)((269.0f - sqrtf((float)(72361 - 8 * p))) * 0.5f);
    i = max(0, min(133, i));
    while (134 * (i + 1) - ((i + 1) * i) / 2 <= p) ++i;
    while (134 * i - (i * (i - 1)) / 2 > p) --i;
    const int j = i + 1 + (p - (134 * i - (i * (i - 1)) / 2));

    float h1[32];
#pragma unroll
    for (int q = 0; q < 8; ++q) {
      const float4 va = *(const float4*)(&sGa[i * 36 + 4 * q]);
      const float4 vb = *(const float4*)(&sGb[j * 36 + 4 * q]);
      h1[4 * q + 0] = fmaxf(va.x + vb.x, 0.f);
      h1[4 * q + 1] = fmaxf(va.y + vb.y, 0.f);
      h1[4 * q + 2] = fmaxf(va.z + vb.z, 0.f);
      h1[4 * q + 3] = fmaxf(va.w + vb.w, 0.f);
    }

    float h2[16];
#pragma unroll
    for (int jj = 0; jj < 16; ++jj) h2[jj] = sb2[jj];
#pragma unroll 8
    for (int ii = 0; ii < 32; ++ii) {
      const float av = h1[ii];
      const float4* wr = reinterpret_cast<const float4*>(&sw2[ii * 16]);
#pragma unroll
      for (int r = 0; r < 4; ++r) {
        float4 w = wr[r];
        h2[4 * r + 0] = fmaf(av, w.x, h2[4 * r + 0]);
        h2[4 * r + 1] = fmaf(av, w.y, h2[4 * r + 1]);
        h2[4 * r + 2] = fmaf(av, w.z, h2[4 * r + 2]);
        h2[4 * r + 3] = fmaf(av, w.w, h2[4 * r + 3]);
      }
    }
#pragma unroll
    for (int jj = 0; jj < 16; ++jj) h2[jj] = fmaxf(h2[jj], 0.f);

    float h3[8];
#pragma unroll
    for (int jj = 0; jj < 8; ++jj) h3[jj] = sb3[jj];
#pragma unroll
    for (int ii = 0; ii < 16; ++ii) {
      const float av = h2[ii];
      const float4* wr = reinterpret_cast<const float4*>(&sw3[ii * 8]);
#pragma unroll
      for (int r = 0; r < 2; ++r) {
        float4 w = wr[r];
        h3[4 * r + 0] = fmaf(av, w.x, h3[4 * r + 0]);
        h3[4 * r + 1] = fmaf(av, w.y, h3[4 * r + 1]);
        h3[4 * r + 2] = fmaf(av, w.z, h3[4 * r + 2]);
        h3[4 * r + 3] = fmaf(av, w.w, h3[4 * r + 3]);
      }
    }
#pragma unroll
    for (int jj = 0; jj < 8; ++jj) h3[jj] = fmaxf(h3[jj], 0.f);

    float z = sb4v[0];
#pragma unroll
    for (int ii = 0; ii < 8; ++ii) z = fmaf(h3[ii], sw4[ii], z);

    const float az = fabsf(z);
    const float e = __expf(-2.f * az);
    const float rr = (1.f - e) / (1.f + e);
    const float val = copysignf(rr, z);

    const int chunk = p >> 5, q8 = (p & 31) >> 3, jj2 = p & 7;
    subjectsA[chunk * 1024 + mtile * 512 + (q8 * 16 + lrm) * 8 + jj2] = f2bf(val);
  }
}

// ---------------------------------------------------------------------------
// c1 (MFMA): C(30x1024) = subjects @ w1. 256 blocks x 4 waves = 1024 jobs.
// ---------------------------------------------------------------------------
__global__ __launch_bounds__(256) void c1_kernel(
    const unsigned short* __restrict__ subjectsA,
    const unsigned short* __restrict__ w1T,
    float* __restrict__ part)
{
  const int t = threadIdx.x;
  const int wv = t >> 6, lane = t & 63, quad = lane >> 4, lr = lane & 15;
  const int job = blockIdx.x * 4 + wv;
  const int ng = job & 15;
  const int kg = job >> 4;
  const int c0 = kg * 5;
  const int cend = min(283, c0 + 5);

  f32x4 acc[2][4] = {};
  for (int ch = c0; ch < cend; ++ch) {
    const bf16x8 a0 = *(const bf16x8*)(subjectsA + ch * 1024 + lane * 8);
    const bf16x8 a1 = *(const bf16x8*)(subjectsA + ch * 1024 + 512 + lane * 8);
#pragma unroll
    for (int nt = 0; nt < 4; ++nt) {
      const int col = (ng * 4 + nt) * 16 + lr;
      const bf16x8 b = *(const bf16x8*)(w1T + (size_t)col * 9088 + ch * 32 + quad * 8);
      acc[0][nt] = __builtin_amdgcn_mfma_f32_16x16x32_bf16(a0, b, acc[0][nt], 0, 0, 0);
      acc[1][nt] = __builtin_amdgcn_mfma_f32_16x16x32_bf16(a1, b, acc[1][nt], 0, 0, 0);
    }
  }
#pragma unroll
  for (int mt = 0; mt < 2; ++mt)
#pragma unroll
    for (int r = 0; r < 4; ++r) {
      const int m = mt * 16 + quad * 4 + r;
      if (m < 30) {
#pragma unroll
        for (int nt = 0; nt < 4; ++nt) {
          const int col = (ng * 4 + nt) * 16 + lr;
          part[(size_t)(m * 64 + kg) * 1024 + col] = acc[mt][nt][r];
        }
      }
    }
}

// ---------------------------------------------------------------------------
// tail_a: reduce 64 partials + rrelu -> act1[30][1024]. 120 blocks.
// ---------------------------------------------------------------------------
__global__ __launch_bounds__(256) void tail_a_kernel(
    const float* __restrict__ part,
    const float* __restrict__ cb1,
    float* __restrict__ act1)
{
  const int r = blockIdx.x >> 2;
  const int cg = blockIdx.x & 3;
  const int j = cg * 256 + threadIdx.x;
  float s = cb1[j];
  const float* pp = part + (size_t)r * 64 * 1024 + j;
#pragma unroll 8
  for (int q = 0; q < 64; ++q) s += pp[q * 1024];
  act1[r * 1024 + j] = s >= 0.f ? s : RRELU_SLOPE * s;
}

// ---------------------------------------------------------------------------
// tail_b: GEMM2 (1024->256) + relu -> act2. 240 blocks.
// ---------------------------------------------------------------------------
__global__ __launch_bounds__(256) void tail_b_kernel(
    const float* __restrict__ act1,
    const float* __restrict__ w2, const float* __restrict__ cb2,
    float* __restrict__ act2)
{
  __shared__ float sa[1024];
  __shared__ float sp[256];
  const int r = blockIdx.x >> 3;
  const int cg = blockIdx.x & 7;
  const int t = threadIdx.x;
  const int c = t & 31;
  const int ks = t >> 5;
  const int col = cg * 32 + c;

  for (int i = t; i < 1024; i += 256) sa[i] = act1[r * 1024 + i];
  __syncthreads();

  float acc = 0.f;
  const int k0 = ks * 128;
  for (int kk = k0; kk < k0 + 128; kk += 4) {
    const float4 a = *reinterpret_cast<const float4*>(&sa[kk]);
    acc = fmaf(a.x, w2[(kk + 0) * 256 + col], acc);
    acc = fmaf(a.y, w2[(kk + 1) * 256 + col], acc);
    acc = fmaf(a.z, w2[(kk + 2) * 256 + col], acc);
    acc = fmaf(a.w, w2[(kk + 3) * 256 + col], acc);
  }
  sp[t] = acc;
  __syncthreads();
  if (t < 32) {
    float s = cb2[col];
#pragma unroll
    for (int q = 0; q < 8; ++q) s += sp[q * 32 + t];
    act2[r * 256 + cg * 32 + t] = fmaxf(s, 0.f);
  }
}

// ---------------------------------------------------------------------------
// tail_c: GEMM3 (256->64, 4-way k-split) + GEMM4 (64->3) + log_softmax.
// ---------------------------------------------------------------------------
__global__ __launch_bounds__(256) void tail_c_kernel(
    const float* __restrict__ act2,
    const float* __restrict__ w3, const float* __restrict__ cb3,
    const float* __restrict__ w4, const float* __restrict__ cb4,
    float* __restrict__ out)
{
  __shared__ float sa[256];
  __shared__ float sp[256];
  __shared__ float sc3[64];
  __shared__ float slg[3];
  const int r = blockIdx.x, t = threadIdx.x;
  const int c = t & 63;
  const int ks = t >> 6;

  sa[t] = act2[r * 256 + t];
  __syncthreads();
  {
    float acc = 0.f;
    const int k0 = ks * 64;
#pragma unroll 4
    for (int kk = k0; kk < k0 + 64; ++kk)
      acc = fmaf(sa[kk], w3[kk * 64 + c], acc);
    sp[t] = acc;
  }
  __syncthreads();
  if (t < 64) {
    const float s = cb3[t] + sp[t] + sp[t + 64] + sp[t + 128] + sp[t + 192];
    sc3[t] = fmaxf(s, 0.f);
  }
  __syncthreads();
  if (t < 3) {
    float acc = cb4[t];
#pragma unroll
    for (int kk = 0; kk < 64; ++kk) acc = fmaf(sc3[kk], w4[kk * 3 + t], acc);
    slg[t] = acc;
  }
  __syncthreads();
  if (t == 0) {
    float m = fmaxf(slg[0], fmaxf(slg[1], slg[2]));
    float se = __expf(slg[0] - m) + __expf(slg[1] - m) + __expf(slg[2] - m);
    float lse = m + logf(se);
    out[r * 3 + 0] = slg[0] - lse;
    out[r * 3 + 1] = slg[1] - lse;
    out[r * 3 + 2] = slg[2] - lse;
  }
}

extern "C" void kernel_launch(void* const* d_in, const int* in_sizes, int n_in,
                              void* d_out, int out_size, void* d_ws, size_t ws_size,
                              hipStream_t stream) {
  const float* x    = (const float*)d_in[0];
  const float* w1c  = (const float*)d_in[1];
  const float* b1c  = (const float*)d_in[2];
  const float* g1   = (const float*)d_in[3];
  const float* bb1  = (const float*)d_in[4];
  const float* w2c  = (const float*)d_in[5];
  const float* b2c  = (const float*)d_in[6];
  const float* g2   = (const float*)d_in[7];
  const float* bb2  = (const float*)d_in[8];
  const float* w3c  = (const float*)d_in[9];
  const float* b3c  = (const float*)d_in[10];
  const float* g3   = (const float*)d_in[11];
  const float* bb3  = (const float*)d_in[12];
  const float* fcw  = (const float*)d_in[13];
  const float* fcb  = (const float*)d_in[14];
  const float* sw1  = (const float*)d_in[15];
  const float* sb1  = (const float*)d_in[16];
  const float* sw2  = (const float*)d_in[17];
  const float* sb2  = (const float*)d_in[18];
  const float* sw3  = (const float*)d_in[19];
  const float* sb3  = (const float*)d_in[20];
  const float* sw4  = (const float*)d_in[21];
  const float* sb4  = (const float*)d_in[22];
  const float* cw1  = (const float*)d_in[23];
  const float* cb1  = (const float*)d_in[24];
  const float* cw2  = (const float*)d_in[25];
  const float* cb2  = (const float*)d_in[26];
  const float* cw3  = (const float*)d_in[27];
  const float* cb3  = (const float*)d_in[28];
  const float* cw4  = (const float*)d_in[29];
  const float* cb4  = (const float*)d_in[30];

  float* ws = (float*)d_ws;
  float* Ga    = ws;                     // 129600
  float* Gb    = ws + 129600;            // -> 259200
  float* part  = ws + 259200;            // 30*64*1024 -> 2225280
  float* bgagb = ws + 2225280;           // 64 -> 2225344
  float* act1  = ws + 2225344;           // 30720 -> 2256064
  float* act2  = ws + 2256064;           // 7680 -> 2263744
  unsigned short* wsu = (unsigned short*)(ws + 2263744);
  unsigned short* w2frag    = wsu;             // 4096 sh
  unsigned short* w3frag    = wsu + 4096;      // -> 13312
  unsigned short* bfragGG   = wsu + 13312;     // -> 152576
  unsigned short* act3      = wsu + 152576;    // -> 8965376
  unsigned short* subjectsA = wsu + 8965376;   // -> 9255168
  unsigned short* w1T       = wsu + 9255168;   // 1024*9088

  setup_kernel<<<2489, 256, 0, stream>>>(w2c, g2, w3c, g3, fcw, fcb, sw1, sb1, cw1,
                                         w2frag, w3frag, bfragGG, bgagb, subjectsA, w1T);
  fe_kernel<<<2025, 128, 0, stream>>>(x, w1c, b1c, g1, bb1, b2c, g2, bb2,
                                      b3c, g3, bb3, w2frag, w3frag, act3);
  gagb_kernel<<<254, 256, 0, stream>>>(act3, bfragGG, bgagb, Ga, Gb);
  sim_kernel<<<960, 256, 0, stream>>>(Ga, Gb, sw2, sb2, sw3, sb3, sw4, sb4, subjectsA);
  c1_kernel<<<256, 256, 0, stream>>>(subjectsA, w1T, part);
  tail_a_kernel<<<120, 256, 0, stream>>>(part, cb1, act1);
  tail_b_kernel<<<240, 256, 0, stream>>>(act1, cw2, cb2, act2);
  tail_c_kernel<<<30, 256, 0, stream>>>(act2, cw3, cb3, cw4, cb4, (float*)d_out);
}